// Round 3
// baseline (4653.875 us; speedup 1.0000x reference)
//
#include <hip/hip_runtime.h>
#include <hip/hip_bf16.h>
#include <cstdint>

#define NUSER 50000
#define NITEM 30000
#define KTOP 50
#define BONUS 0.05f
#define CHUNK 12800

__device__ __forceinline__ float sigf(float x){ return 1.0f/(1.0f + __expf(-x)); }
// monotone float->uint map: larger float <-> larger uint
__device__ __forceinline__ unsigned fmap(float x){ unsigned b=__float_as_uint(x); return (b&0x80000000u)? ~b : (b|0x80000000u); }

__global__ void k_init(int* deg_i, int* inv, int* keep0, int* cidx, int N, int Bq){
  int i = blockIdx.x*blockDim.x + threadIdx.x;
  if(i < N){ deg_i[i]=0; inv[i]=-1; keep0[i]=0; }
  if(i < Bq) cidx[i]=0x7FFFFFFF;
}

// tiny GEMM (thread per output) for gi_table (27x384)
__global__ void k_small_gemm(const float* __restrict__ A, const float* __restrict__ W,
                             const float* __restrict__ bias, float* __restrict__ C,
                             int M, int Nn, int Kk){
  int i = blockIdx.x*blockDim.x + threadIdx.x;
  if(i >= M*Nn) return;
  int r = i/Nn, c = i - r*Nn;
  float acc = bias ? bias[c] : 0.f;
  for(int k=0;k<Kk;k++) acc = fmaf(A[r*Kk+k], W[k*Nn+c], acc);
  C[i] = acc;
}

// repack W_pna rows [0:1536] into Wbig (512 x 384): Wbig[k][s*128+j] = W_pna[s*512+k][j]
__global__ void k_wbig(const float* __restrict__ Wp, float* __restrict__ Wbig){
  int i = blockIdx.x*blockDim.x + threadIdx.x;
  if(i >= 512*384) return;
  int k = i/384, c = i - k*384;
  int slice = c>>7, j = c&127;
  Wbig[i] = Wp[(slice*512 + k)*128 + j];
}

// f32 tiled GEMM: C[MxN] = A[MxK] @ B[KxN] (+bias per col), A row-major
__global__ __launch_bounds__(256)
void k_gemm(const float* __restrict__ A, const float* __restrict__ Bm,
            const float* __restrict__ bias, float* __restrict__ C,
            int M, int Nn, int Kk){
  __shared__ float As[32][68];
  __shared__ float Bs[32][64];
  int tid = threadIdx.x;
  int tx = tid & 15, ty = tid >> 4;
  int bm = blockIdx.x*64, bn = blockIdx.y*64;
  float acc[4][4] = {};
  for(int k0=0;k0<Kk;k0+=32){
    #pragma unroll
    for(int l=0;l<8;l++){
      int li = tid + l*256;
      int c = li & 31, r = li >> 5;
      int row = bm + r;
      float v = 0.f;
      if(row < M) v = A[(long long)row*Kk + k0 + c];
      As[c][r] = v;
    }
    #pragma unroll
    for(int l=0;l<8;l++){
      int li = tid + l*256;
      int j = li & 63, c = li >> 6;
      Bs[c][j] = Bm[(long long)(k0+c)*Nn + bn + j];
    }
    __syncthreads();
    #pragma unroll
    for(int k=0;k<32;k++){
      float4 a4 = *(const float4*)&As[k][ty*4];
      float4 b4 = *(const float4*)&Bs[k][tx*4];
      float av[4]={a4.x,a4.y,a4.z,a4.w};
      float bv[4]={b4.x,b4.y,b4.z,b4.w};
      #pragma unroll
      for(int ii=0;ii<4;ii++)
        #pragma unroll
        for(int jj=0;jj<4;jj++)
          acc[ii][jj] = fmaf(av[ii], bv[jj], acc[ii][jj]);
    }
    __syncthreads();
  }
  #pragma unroll
  for(int ii=0;ii<4;ii++){
    int row = bm + ty*4 + ii;
    if(row >= M) continue;
    float4 o;
    o.x=acc[ii][0]; o.y=acc[ii][1]; o.z=acc[ii][2]; o.w=acc[ii][3];
    if(bias){ int cb = bn + tx*4; o.x+=bias[cb]; o.y+=bias[cb+1]; o.z+=bias[cb+2]; o.w+=bias[cb+3]; }
    *(float4*)&C[(long long)row*Nn + bn + tx*4] = o;
  }
}

__global__ void k_scatter_old(const int* __restrict__ oni, int* __restrict__ inv,
                              int* __restrict__ keep0, int NP, int N){
  int i = blockIdx.x*blockDim.x + threadIdx.x;
  if(i>=NP) return;
  int v = oni[i];
  if(v>=0 && v<N){ inv[v]=i; keep0[v]=1; }
}

// ---- CSR build ----
__global__ void k_count(const int* __restrict__ edges, int* __restrict__ deg_i, int E){
  int e = blockIdx.x*blockDim.x + threadIdx.x;
  if(e<E) atomicAdd(&deg_i[edges[(long long)e*6+5]], 1);
}

__global__ __launch_bounds__(256)
void k_scan1(const int* __restrict__ deg_i, int* __restrict__ rowptr, int* __restrict__ bsum, int N){
  __shared__ int sc[256];
  int tid=threadIdx.x; int i = blockIdx.x*256+tid;
  int v = (i<N)? deg_i[i] : 0;
  sc[tid]=v; __syncthreads();
  for(int off=1; off<256; off<<=1){
    int t = (tid>=off)? sc[tid-off] : 0;
    __syncthreads();
    sc[tid] += t;
    __syncthreads();
  }
  if(i<N) rowptr[i] = sc[tid] - v;       // exclusive intra-block
  if(tid==255) bsum[blockIdx.x] = sc[255];
}

__global__ void k_scan2(int* bsum, int nb){
  if(threadIdx.x==0 && blockIdx.x==0){
    int run=0;
    for(int j=0;j<nb;j++){ int t=bsum[j]; bsum[j]=run; run+=t; }
  }
}

__global__ void k_scan3(int* __restrict__ rowptr, const int* __restrict__ bsum,
                        int* __restrict__ cursor, int N, int E){
  int i = blockIdx.x*blockDim.x + threadIdx.x;
  if(i<N){ int r = rowptr[i] + bsum[i>>8]; rowptr[i]=r; cursor[i]=r; }
  if(i==0) rowptr[N]=E;
}

__global__ void k_fill(const int* __restrict__ edges, int* __restrict__ cursor,
                       int* __restrict__ eid, int E){
  int e = blockIdx.x*blockDim.x + threadIdx.x;
  if(e<E){ int obj = edges[(long long)e*6+5]; int p = atomicAdd(&cursor[obj],1); eid[p]=e; }
}

// ---- per-node aggregation (one wave per node), agg row = [mean|std|min|max] (512 f32) ----
__global__ __launch_bounds__(256)
void k_aggcsr(const int* __restrict__ edges, const int* __restrict__ eid,
              const int* __restrict__ rowptr, const float* __restrict__ gi_t,
              const float* __restrict__ gh_t, const float* __restrict__ hidden,
              float* __restrict__ agg, int base, int M){
  int wid = (blockIdx.x*256 + threadIdx.x)>>6;
  int lane = threadIdx.x & 63;
  if(wid >= M) return;
  int v = base + wid;
  int r0 = rowptr[v], r1 = rowptr[v+1];
  float s0=0.f, q0=0.f, s1v=0.f, q1=0.f;
  float mn0=INFINITY, mx0=-INFINITY, mn1=INFINITY, mx1=-INFINITY;
  for(int j=r0;j<r1;++j){
    int e = eid[j];
    const int* er = edges + (long long)e*6;
    int sub = er[4], rel = er[2];
    const float* gi = gi_t + (long long)rel*384;
    const float* gh = gh_t + (long long)sub*384;
    const float* hs = hidden + (long long)sub*128;
    {
      int d = lane;
      float r = sigf(gi[d]+gh[d]);
      float z = sigf(gi[128+d]+gh[128+d]);
      float n = tanhf(gi[256+d] + r*gh[256+d]);
      float m = (1.f-z)*n + z*hs[d];
      s0+=m; q0=fmaf(m,m,q0); mn0=fminf(mn0,m); mx0=fmaxf(mx0,m);
    }
    {
      int d = lane+64;
      float r = sigf(gi[d]+gh[d]);
      float z = sigf(gi[128+d]+gh[128+d]);
      float n = tanhf(gi[256+d] + r*gh[256+d]);
      float m = (1.f-z)*n + z*hs[d];
      s1v+=m; q1=fmaf(m,m,q1); mn1=fminf(mn1,m); mx1=fmaxf(mx1,m);
    }
  }
  float dg = (float)(r1-r0);
  float dc = fmaxf(dg, 1.f);
  bool has = dg > 0.f;
  float* a = agg + (long long)wid*512;
  {
    float mean = s0/dc;
    float var = q0/dc - mean*mean;
    float sd = sqrtf(fmaxf(var,0.f)+1e-5f);
    a[lane]=mean; a[128+lane]=sd;
    a[256+lane]= has? mn0 : 0.f; a[384+lane]= has? mx0 : 0.f;
  }
  {
    float mean = s1v/dc;
    float var = q1/dc - mean*mean;
    float sd = sqrtf(fmaxf(var,0.f)+1e-5f);
    a[64+lane]=mean; a[192+lane]=sd;
    a[320+lane]= has? mn1 : 0.f; a[448+lane]= has? mx1 : 0.f;
  }
}

// ---- fused PNA GEMM: hout[v] = acc0 + logd*acc1 + att*acc2 + b_pna + hp[inv[v]] ----
__global__ __launch_bounds__(256)
void k_gemm_fused(const float* __restrict__ A, const float* __restrict__ Wb,
                  const int* __restrict__ rowptr, const int* __restrict__ inv,
                  const float* __restrict__ hp, const float* __restrict__ b_pna,
                  float* __restrict__ hout, int base, int M){
  __shared__ float As[32][68];
  __shared__ float Bs[3][32][64];
  int tid = threadIdx.x;
  int tx = tid & 15, ty = tid >> 4;
  int bm = blockIdx.x*64, bn = blockIdx.y*64;
  float acc[3][4][4] = {};
  for(int k0=0;k0<512;k0+=32){
    #pragma unroll
    for(int l=0;l<8;l++){
      int li = tid + l*256;
      int c = li & 31, r = li >> 5;
      int row = bm + r;
      float v = 0.f;
      if(row < M) v = A[(long long)row*512 + k0 + c];
      As[c][r] = v;
    }
    #pragma unroll
    for(int s=0;s<3;s++){
      #pragma unroll
      for(int l=0;l<8;l++){
        int li = tid + l*256;
        int j = li & 63, c = li >> 6;
        Bs[s][c][j] = Wb[(long long)(k0+c)*384 + s*128 + bn + j];
      }
    }
    __syncthreads();
    #pragma unroll
    for(int k=0;k<32;k++){
      float4 a4 = *(const float4*)&As[k][ty*4];
      float av[4]={a4.x,a4.y,a4.z,a4.w};
      #pragma unroll
      for(int s=0;s<3;s++){
        float4 b4 = *(const float4*)&Bs[s][k][tx*4];
        float bv[4]={b4.x,b4.y,b4.z,b4.w};
        #pragma unroll
        for(int ii=0;ii<4;ii++)
          #pragma unroll
          for(int jj=0;jj<4;jj++)
            acc[s][ii][jj] = fmaf(av[ii], bv[jj], acc[s][ii][jj]);
      }
    }
    __syncthreads();
  }
  int col = bn + tx*4;
  float4 bp = *(const float4*)&b_pna[col];
  #pragma unroll
  for(int ii=0;ii<4;ii++){
    int rl = bm + ty*4 + ii;
    if(rl >= M) continue;
    int v = base + rl;
    float dg = (float)(rowptr[v+1]-rowptr[v]);
    float logd = log1pf(dg);          // amp = logd/DELTA, DELTA=1
    float att = 1.0f/(logd + 1.0f);
    float o0 = acc[0][ii][0] + logd*acc[1][ii][0] + att*acc[2][ii][0] + bp.x;
    float o1 = acc[0][ii][1] + logd*acc[1][ii][1] + att*acc[2][ii][1] + bp.y;
    float o2 = acc[0][ii][2] + logd*acc[1][ii][2] + att*acc[2][ii][2] + bp.z;
    float o3 = acc[0][ii][3] + logd*acc[1][ii][3] + att*acc[2][ii][3] + bp.w;
    int iv = inv[v];
    if(iv>=0){
      float4 h4 = *(const float4*)&hp[(long long)iv*128 + col];
      o0+=h4.x; o1+=h4.y; o2+=h4.z; o3+=h4.w;
    }
    float4 o; o.x=o0; o.y=o1; o.z=o2; o.w=o3;
    *(float4*)&hout[(long long)v*128 + col] = o;
  }
}

__global__ void k_center(const int* __restrict__ nodes, const int* __restrict__ q_sub,
                         int* __restrict__ cidx, int N, int Bq){
  int i = blockIdx.x*blockDim.x + threadIdx.x;
  if(i>=N) return;
  int b = nodes[2*i];
  if(b>=0 && b<Bq && nodes[2*i+1]==q_sub[b]) atomicMin((unsigned*)&cidx[b], (unsigned)i);
}

__global__ __launch_bounds__(64)
void k_cu(const float* __restrict__ hout, const int* __restrict__ cidx,
          const float* __restrict__ Wsc, float* __restrict__ cu, int Bq){
  int b = blockIdx.x, lane = threadIdx.x;
  int i = cidx[b]; if(i==0x7FFFFFFF) i=0;
  const float* hrow = hout + (long long)i*128;
  float p = fmaf(hrow[lane], Wsc[lane], hrow[64+lane]*Wsc[64+lane]);
  for(int o=32;o>0;o>>=1) p += __shfl_down(p, o);
  if(lane==0) cu[b]=p;
}

__global__ __launch_bounds__(64)
void k_alpha(float* __restrict__ hout, const int* __restrict__ nodes,
             const float* __restrict__ cu, const float* __restrict__ Wsc,
             const float* __restrict__ b_sc, const int* __restrict__ keep0,
             float* __restrict__ out_alpha, float* __restrict__ out_keep,
             float* __restrict__ ca, int N){
  int v = blockIdx.x, lane = threadIdx.x;
  float* hrow = hout + (long long)v*128;
  float h0 = hrow[lane], h1 = hrow[64+lane];
  float p = fmaf(h0, Wsc[128+lane], h1*Wsc[192+lane]);
  for(int o=32;o>0;o>>=1) p += __shfl_down(p,o);
  float t = __shfl(p, 0);
  int bnode = nodes[2*v];
  t += cu[bnode] + b_sc[0];
  float alpha = sigf(t);   // TAU = 1
  hrow[lane] = alpha*h0;
  hrow[64+lane] = alpha*h1;
  if(lane==0){
    out_alpha[v] = alpha;
    out_keep[v] = 0.f;
    int ent = nodes[2*v+1];
    ca[v] = keep0[v] ? -__builtin_inff() : (alpha + ((ent>=NUSER && ent<NUSER+NITEM)?BONUS:0.f));
  }
}

// exact per-batch top-K via binary search on float bit space, index-ordered ties
__global__ __launch_bounds__(256)
void k_topk(const float* __restrict__ ca, const int* __restrict__ nodes,
            const int* __restrict__ idl, const int* __restrict__ nl,
            float* __restrict__ out_keep, int N){
  if(idl[0] >= nl[0]-1) return;
  int b = blockIdx.x;
  int tid = threadIdx.x;
  __shared__ int red[256];
  __shared__ int s_sel;

  auto countGE = [&](unsigned thr)->int{
    int c = 0;
    for(int i=tid;i<N;i+=256)
      if(nodes[2*i]==b && fmap(ca[i]) >= thr) c++;
    red[tid]=c; __syncthreads();
    for(int o=128;o>0;o>>=1){ if(tid<o) red[tid]+=red[tid+o]; __syncthreads(); }
    int r = red[0]; __syncthreads();
    return r;
  };

  int c_all = countGE(0x80000000u);  // all candidates (ca >= +0.0; -inf for non-cand)
  if(c_all <= KTOP){
    for(int i=tid;i<N;i+=256)
      if(nodes[2*i]==b && fmap(ca[i]) >= 0x80000000u) out_keep[i]=1.f;
    return;
  }
  unsigned lo=0x80000000u, hi=0xFFFFFFFFu;
  while(hi - lo > 1u){
    unsigned mid = lo + ((hi-lo)>>1);
    int c = countGE(mid);
    if(c >= KTOP) lo = mid; else hi = mid;
  }
  unsigned ustar = lo;              // mapped K-th largest value
  int nG  = countGE(ustar+1u);
  int cGE = countGE(ustar);
  int cEq = cGE - nG;
  int rrem = KTOP - nG;
  for(int i=tid;i<N;i+=256)
    if(nodes[2*i]==b && fmap(ca[i]) > ustar) out_keep[i]=1.f;
  if(cEq <= rrem){
    for(int i=tid;i<N;i+=256)
      if(nodes[2*i]==b && fmap(ca[i]) == ustar) out_keep[i]=1.f;
  } else {
    int sel = -1;
    for(int t=0;t<rrem;t++){
      int lmin = 0x7FFFFFFF;
      for(int i=tid;i<N;i+=256)
        if(i>sel && nodes[2*i]==b && fmap(ca[i])==ustar && i<lmin) lmin=i;
      red[tid]=lmin; __syncthreads();
      for(int o=128;o>0;o>>=1){ if(tid<o) red[tid]=min(red[tid],red[tid+o]); __syncthreads(); }
      if(tid==0){ s_sel = red[0]; if(red[0]!=0x7FFFFFFF) out_keep[red[0]]=1.f; }
      __syncthreads();
      sel = s_sel;
      __syncthreads();
    }
  }
}

__global__ void k_keepfin(const int* __restrict__ nodes, const int* __restrict__ keep0,
                          const int* __restrict__ idl, const int* __restrict__ nl,
                          float* __restrict__ out_keep, int N){
  int i = blockIdx.x*blockDim.x + threadIdx.x;
  if(i>=N) return;
  if(idl[0] < nl[0]-1){
    if(keep0[i]) out_keep[i]=1.f;
  } else {
    int ent = nodes[2*i+1];
    out_keep[i] = (ent>=NUSER && ent<NUSER+NITEM) ? 1.f : 0.f;
  }
}

extern "C" void kernel_launch(void* const* d_in, const int* in_sizes, int n_in,
                              void* d_out, int out_size, void* d_ws, size_t ws_size,
                              hipStream_t stream){
  const int*   q_sub    = (const int*)d_in[0];
  const float* hidden   = (const float*)d_in[2];
  const int*   edges    = (const int*)d_in[3];
  const int*   nodes    = (const int*)d_in[4];
  const int*   idl      = (const int*)d_in[5];
  const int*   nl       = (const int*)d_in[6];
  const int*   oni      = (const int*)d_in[7];
  const float* rel_tab  = (const float*)d_in[8];
  const float* W_i      = (const float*)d_in[9];
  const float* W_h      = (const float*)d_in[10];
  const float* b_i      = (const float*)d_in[11];
  const float* b_h      = (const float*)d_in[12];
  const float* W_pna    = (const float*)d_in[13];
  const float* b_pna    = (const float*)d_in[14];
  const float* W_sc     = (const float*)d_in[15];
  const float* b_sc     = (const float*)d_in[16];

  int Bq = in_sizes[0];
  int NP = in_sizes[2]/128;
  int E  = in_sizes[3]/6;
  int N  = in_sizes[4]/2;
  int NR = in_sizes[8]/128;
  long long nd = (long long)N*128;
  int nb = (N+255)/256;

  size_t off = 0;
  auto alloc = [&](size_t bytes)->void*{
    void* r = (char*)d_ws + off;
    off += (bytes + 255) & ~(size_t)255;
    return r;
  };
  float* agg    = (float*)alloc((size_t)CHUNK*512*4);   // 26.2 MB, reused per chunk
  float* gh_t   = (float*)alloc((size_t)NP*384*4);      // 30.7 MB
  float* gi_t   = (float*)alloc((size_t)NR*384*4);
  float* wbig   = (float*)alloc((size_t)512*384*4);
  float* hp     = (float*)alloc((size_t)NP*128*4);      // 10.2 MB
  int*   rowptr = (int*)  alloc((size_t)(N+1)*4);
  int*   cursor = (int*)  alloc((size_t)N*4);
  int*   deg_i  = (int*)  alloc((size_t)N*4);
  int*   bsum   = (int*)  alloc((size_t)nb*4);
  int*   eid    = (int*)  alloc((size_t)E*4);
  int*   inv    = (int*)  alloc((size_t)N*4);
  int*   kp0    = (int*)  alloc((size_t)N*4);
  int*   cidx   = (int*)  alloc((size_t)Bq*4);
  float* cu     = (float*)alloc((size_t)Bq*4);
  float* ca     = (float*)alloc((size_t)N*4);
  // total ~71.5 MB

  float* out_h = (float*)d_out;
  float* out_alpha = out_h + nd;
  float* out_keep = out_alpha + N;

  k_init<<<(N+255)/256,256,0,stream>>>(deg_i, inv, kp0, cidx, N, Bq);
  k_small_gemm<<<(NR*384+255)/256,256,0,stream>>>(rel_tab, W_i, b_i, gi_t, NR, 384, 128);
  k_gemm<<<dim3((NP+63)/64, 384/64),256,0,stream>>>(hidden, W_h, b_h, gh_t, NP, 384, 128);
  k_wbig<<<(512*384+255)/256,256,0,stream>>>(W_pna, wbig);
  k_gemm<<<dim3((NP+63)/64, 128/64),256,0,stream>>>(hidden, W_pna + 1536*128, nullptr, hp, NP, 128, 128);
  k_scatter_old<<<(NP+255)/256,256,0,stream>>>(oni, inv, kp0, NP, N);
  k_count<<<(E+255)/256,256,0,stream>>>(edges, deg_i, E);
  k_scan1<<<nb,256,0,stream>>>(deg_i, rowptr, bsum, N);
  k_scan2<<<1,64,0,stream>>>(bsum, nb);
  k_scan3<<<(N+255)/256,256,0,stream>>>(rowptr, bsum, cursor, N, E);
  k_fill<<<(E+255)/256,256,0,stream>>>(edges, cursor, eid, E);
  for(int base=0; base<N; base+=CHUNK){
    int M = (N-base < CHUNK) ? (N-base) : CHUNK;
    k_aggcsr<<<((size_t)M*64+255)/256,256,0,stream>>>(edges, eid, rowptr, gi_t, gh_t, hidden, agg, base, M);
    k_gemm_fused<<<dim3((M+63)/64, 2),256,0,stream>>>(agg, wbig, rowptr, inv, hp, b_pna, out_h, base, M);
  }
  k_center<<<(N+255)/256,256,0,stream>>>(nodes, q_sub, cidx, N, Bq);
  k_cu<<<Bq,64,0,stream>>>(out_h, cidx, W_sc, cu, Bq);
  k_alpha<<<N,64,0,stream>>>(out_h, nodes, cu, W_sc, b_sc, kp0, out_alpha, out_keep, ca, N);
  k_topk<<<Bq,256,0,stream>>>(ca, nodes, idl, nl, out_keep, N);
  k_keepfin<<<(N+255)/256,256,0,stream>>>(nodes, kp0, idl, nl, out_keep, N);
}

// Round 4
// 1520.205 us; speedup vs baseline: 3.0613x; 3.0613x over previous
//
#include <hip/hip_runtime.h>
#include <hip/hip_bf16.h>
#include <cstdint>

#define NUSER 50000
#define NITEM 30000
#define KTOP 50
#define BONUS 0.05f
#define CHUNK 12800

__device__ __forceinline__ float sigf(float x){ return 1.0f/(1.0f + __expf(-x)); }
// monotone float->uint map: larger float <-> larger uint
__device__ __forceinline__ unsigned fmap(float x){ unsigned b=__float_as_uint(x); return (b&0x80000000u)? ~b : (b|0x80000000u); }

__global__ void k_init(int* deg_i, int* inv, int* keep0, int* cidx, int* ccnt, int N, int Bq){
  int i = blockIdx.x*blockDim.x + threadIdx.x;
  if(i < N){ deg_i[i]=0; inv[i]=-1; keep0[i]=0; }
  if(i < Bq){ cidx[i]=0x7FFFFFFF; ccnt[i]=0; }
}

// tiny GEMM (thread per output) for gi_table (27x384)
__global__ void k_small_gemm(const float* __restrict__ A, const float* __restrict__ W,
                             const float* __restrict__ bias, float* __restrict__ C,
                             int M, int Nn, int Kk){
  int i = blockIdx.x*blockDim.x + threadIdx.x;
  if(i >= M*Nn) return;
  int r = i/Nn, c = i - r*Nn;
  float acc = bias ? bias[c] : 0.f;
  for(int k=0;k<Kk;k++) acc = fmaf(A[r*Kk+k], W[k*Nn+c], acc);
  C[i] = acc;
}

// repack W_pna rows [0:1536] into Wbig (512 x 384): Wbig[k][s*128+j] = W_pna[s*512+k][j]
__global__ void k_wbig(const float* __restrict__ Wp, float* __restrict__ Wbig){
  int i = blockIdx.x*blockDim.x + threadIdx.x;
  if(i >= 512*384) return;
  int k = i/384, c = i - k*384;
  int slice = c>>7, j = c&127;
  Wbig[i] = Wp[(slice*512 + k)*128 + j];
}

// f32 tiled GEMM: C[MxN] = A[MxK] @ B[KxN] (+bias per col), A row-major
__global__ __launch_bounds__(256)
void k_gemm(const float* __restrict__ A, const float* __restrict__ Bm,
            const float* __restrict__ bias, float* __restrict__ C,
            int M, int Nn, int Kk){
  __shared__ float As[32][68];
  __shared__ float Bs[32][64];
  int tid = threadIdx.x;
  int tx = tid & 15, ty = tid >> 4;
  int bm = blockIdx.x*64, bn = blockIdx.y*64;
  float acc[4][4] = {};
  for(int k0=0;k0<Kk;k0+=32){
    #pragma unroll
    for(int l=0;l<8;l++){
      int li = tid + l*256;
      int c = li & 31, r = li >> 5;
      int row = bm + r;
      float v = 0.f;
      if(row < M) v = A[(long long)row*Kk + k0 + c];
      As[c][r] = v;
    }
    #pragma unroll
    for(int l=0;l<8;l++){
      int li = tid + l*256;
      int j = li & 63, c = li >> 6;
      Bs[c][j] = Bm[(long long)(k0+c)*Nn + bn + j];
    }
    __syncthreads();
    #pragma unroll
    for(int k=0;k<32;k++){
      float4 a4 = *(const float4*)&As[k][ty*4];
      float4 b4 = *(const float4*)&Bs[k][tx*4];
      float av[4]={a4.x,a4.y,a4.z,a4.w};
      float bv[4]={b4.x,b4.y,b4.z,b4.w};
      #pragma unroll
      for(int ii=0;ii<4;ii++)
        #pragma unroll
        for(int jj=0;jj<4;jj++)
          acc[ii][jj] = fmaf(av[ii], bv[jj], acc[ii][jj]);
    }
    __syncthreads();
  }
  #pragma unroll
  for(int ii=0;ii<4;ii++){
    int row = bm + ty*4 + ii;
    if(row >= M) continue;
    float4 o;
    o.x=acc[ii][0]; o.y=acc[ii][1]; o.z=acc[ii][2]; o.w=acc[ii][3];
    if(bias){ int cb = bn + tx*4; o.x+=bias[cb]; o.y+=bias[cb+1]; o.z+=bias[cb+2]; o.w+=bias[cb+3]; }
    *(float4*)&C[(long long)row*Nn + bn + tx*4] = o;
  }
}

__global__ void k_scatter_old(const int* __restrict__ oni, int* __restrict__ inv,
                              int* __restrict__ keep0, int NP, int N){
  int i = blockIdx.x*blockDim.x + threadIdx.x;
  if(i>=NP) return;
  int v = oni[i];
  if(v>=0 && v<N){ inv[v]=i; keep0[v]=1; }
}

// ---- CSR build ----
__global__ void k_count(const int* __restrict__ edges, int* __restrict__ deg_i, int E){
  int e = blockIdx.x*blockDim.x + threadIdx.x;
  if(e<E) atomicAdd(&deg_i[edges[(long long)e*6+5]], 1);
}

__global__ __launch_bounds__(256)
void k_scan1(const int* __restrict__ deg_i, int* __restrict__ rowptr, int* __restrict__ bsum, int N){
  __shared__ int sc[256];
  int tid=threadIdx.x; int i = blockIdx.x*256+tid;
  int v = (i<N)? deg_i[i] : 0;
  sc[tid]=v; __syncthreads();
  for(int off=1; off<256; off<<=1){
    int t = (tid>=off)? sc[tid-off] : 0;
    __syncthreads();
    sc[tid] += t;
    __syncthreads();
  }
  if(i<N) rowptr[i] = sc[tid] - v;       // exclusive intra-block
  if(tid==255) bsum[blockIdx.x] = sc[255];
}

__global__ void k_scan2(int* bsum, int nb){
  if(threadIdx.x==0 && blockIdx.x==0){
    int run=0;
    for(int j=0;j<nb;j++){ int t=bsum[j]; bsum[j]=run; run+=t; }
  }
}

__global__ void k_scan3(int* __restrict__ rowptr, const int* __restrict__ bsum,
                        int* __restrict__ cursor, int N, int E){
  int i = blockIdx.x*blockDim.x + threadIdx.x;
  if(i<N){ int r = rowptr[i] + bsum[i>>8]; rowptr[i]=r; cursor[i]=r; }
  if(i==0) rowptr[N]=E;
}

__global__ void k_fill(const int* __restrict__ edges, int* __restrict__ cursor,
                       int* __restrict__ eid, int E){
  int e = blockIdx.x*blockDim.x + threadIdx.x;
  if(e<E){ int obj = edges[(long long)e*6+5]; int p = atomicAdd(&cursor[obj],1); eid[p]=e; }
}

// ---- per-node aggregation (one wave per node), agg row = [mean|std|min|max] (512 f32) ----
__global__ __launch_bounds__(256)
void k_aggcsr(const int* __restrict__ edges, const int* __restrict__ eid,
              const int* __restrict__ rowptr, const float* __restrict__ gi_t,
              const float* __restrict__ gh_t, const float* __restrict__ hidden,
              float* __restrict__ agg, int base, int M){
  int wid = (blockIdx.x*256 + threadIdx.x)>>6;
  int lane = threadIdx.x & 63;
  if(wid >= M) return;
  int v = base + wid;
  int r0 = rowptr[v], r1 = rowptr[v+1];
  float s0=0.f, q0=0.f, s1v=0.f, q1=0.f;
  float mn0=INFINITY, mx0=-INFINITY, mn1=INFINITY, mx1=-INFINITY;
  for(int j=r0;j<r1;++j){
    int e = eid[j];
    const int* er = edges + (long long)e*6;
    int sub = er[4], rel = er[2];
    const float* gi = gi_t + (long long)rel*384;
    const float* gh = gh_t + (long long)sub*384;
    const float* hs = hidden + (long long)sub*128;
    {
      int d = lane;
      float r = sigf(gi[d]+gh[d]);
      float z = sigf(gi[128+d]+gh[128+d]);
      float n = tanhf(gi[256+d] + r*gh[256+d]);
      float m = (1.f-z)*n + z*hs[d];
      s0+=m; q0=fmaf(m,m,q0); mn0=fminf(mn0,m); mx0=fmaxf(mx0,m);
    }
    {
      int d = lane+64;
      float r = sigf(gi[d]+gh[d]);
      float z = sigf(gi[128+d]+gh[128+d]);
      float n = tanhf(gi[256+d] + r*gh[256+d]);
      float m = (1.f-z)*n + z*hs[d];
      s1v+=m; q1=fmaf(m,m,q1); mn1=fminf(mn1,m); mx1=fmaxf(mx1,m);
    }
  }
  float dg = (float)(r1-r0);
  float dc = fmaxf(dg, 1.f);
  bool has = dg > 0.f;
  float* a = agg + (long long)wid*512;
  {
    float mean = s0/dc;
    float var = q0/dc - mean*mean;
    float sd = sqrtf(fmaxf(var,0.f)+1e-5f);
    a[lane]=mean; a[128+lane]=sd;
    a[256+lane]= has? mn0 : 0.f; a[384+lane]= has? mx0 : 0.f;
  }
  {
    float mean = s1v/dc;
    float var = q1/dc - mean*mean;
    float sd = sqrtf(fmaxf(var,0.f)+1e-5f);
    a[64+lane]=mean; a[192+lane]=sd;
    a[320+lane]= has? mn1 : 0.f; a[448+lane]= has? mx1 : 0.f;
  }
}

// ---- fused PNA GEMM: hout[v] = acc0 + logd*acc1 + att*acc2 + b_pna + hp[inv[v]] ----
__global__ __launch_bounds__(256)
void k_gemm_fused(const float* __restrict__ A, const float* __restrict__ Wb,
                  const int* __restrict__ rowptr, const int* __restrict__ inv,
                  const float* __restrict__ hp, const float* __restrict__ b_pna,
                  float* __restrict__ hout, int base, int M){
  __shared__ float As[32][68];
  __shared__ float Bs[3][32][64];
  int tid = threadIdx.x;
  int tx = tid & 15, ty = tid >> 4;
  int bm = blockIdx.x*64, bn = blockIdx.y*64;
  float acc[3][4][4] = {};
  for(int k0=0;k0<512;k0+=32){
    #pragma unroll
    for(int l=0;l<8;l++){
      int li = tid + l*256;
      int c = li & 31, r = li >> 5;
      int row = bm + r;
      float v = 0.f;
      if(row < M) v = A[(long long)row*512 + k0 + c];
      As[c][r] = v;
    }
    #pragma unroll
    for(int s=0;s<3;s++){
      #pragma unroll
      for(int l=0;l<8;l++){
        int li = tid + l*256;
        int j = li & 63, c = li >> 6;
        Bs[s][c][j] = Wb[(long long)(k0+c)*384 + s*128 + bn + j];
      }
    }
    __syncthreads();
    #pragma unroll
    for(int k=0;k<32;k++){
      float4 a4 = *(const float4*)&As[k][ty*4];
      float av[4]={a4.x,a4.y,a4.z,a4.w};
      #pragma unroll
      for(int s=0;s<3;s++){
        float4 b4 = *(const float4*)&Bs[s][k][tx*4];
        float bv[4]={b4.x,b4.y,b4.z,b4.w};
        #pragma unroll
        for(int ii=0;ii<4;ii++)
          #pragma unroll
          for(int jj=0;jj<4;jj++)
            acc[s][ii][jj] = fmaf(av[ii], bv[jj], acc[s][ii][jj]);
      }
    }
    __syncthreads();
  }
  int col = bn + tx*4;
  float4 bp = *(const float4*)&b_pna[col];
  #pragma unroll
  for(int ii=0;ii<4;ii++){
    int rl = bm + ty*4 + ii;
    if(rl >= M) continue;
    int v = base + rl;
    float dg = (float)(rowptr[v+1]-rowptr[v]);
    float logd = log1pf(dg);          // amp = logd/DELTA, DELTA=1
    float att = 1.0f/(logd + 1.0f);
    float o0 = acc[0][ii][0] + logd*acc[1][ii][0] + att*acc[2][ii][0] + bp.x;
    float o1 = acc[0][ii][1] + logd*acc[1][ii][1] + att*acc[2][ii][1] + bp.y;
    float o2 = acc[0][ii][2] + logd*acc[1][ii][2] + att*acc[2][ii][2] + bp.z;
    float o3 = acc[0][ii][3] + logd*acc[1][ii][3] + att*acc[2][ii][3] + bp.w;
    int iv = inv[v];
    if(iv>=0){
      float4 h4 = *(const float4*)&hp[(long long)iv*128 + col];
      o0+=h4.x; o1+=h4.y; o2+=h4.z; o3+=h4.w;
    }
    float4 o; o.x=o0; o.y=o1; o.z=o2; o.w=o3;
    *(float4*)&hout[(long long)v*128 + col] = o;
  }
}

__global__ void k_center(const int* __restrict__ nodes, const int* __restrict__ q_sub,
                         int* __restrict__ cidx, int N, int Bq){
  int i = blockIdx.x*blockDim.x + threadIdx.x;
  if(i>=N) return;
  int b = nodes[2*i];
  if(b>=0 && b<Bq && nodes[2*i+1]==q_sub[b]) atomicMin((unsigned*)&cidx[b], (unsigned)i);
}

__global__ __launch_bounds__(64)
void k_cu(const float* __restrict__ hout, const int* __restrict__ cidx,
          const float* __restrict__ Wsc, float* __restrict__ cu, int Bq){
  int b = blockIdx.x, lane = threadIdx.x;
  int i = cidx[b]; if(i==0x7FFFFFFF) i=0;
  const float* hrow = hout + (long long)i*128;
  float p = fmaf(hrow[lane], Wsc[lane], hrow[64+lane]*Wsc[64+lane]);
  for(int o=32;o>0;o>>=1) p += __shfl_down(p, o);
  if(lane==0) cu[b]=p;
}

__global__ __launch_bounds__(64)
void k_alpha(float* __restrict__ hout, const int* __restrict__ nodes,
             const float* __restrict__ cu, const float* __restrict__ Wsc,
             const float* __restrict__ b_sc, const int* __restrict__ keep0,
             float* __restrict__ out_alpha, float* __restrict__ out_keep,
             float* __restrict__ ca, int N){
  int v = blockIdx.x, lane = threadIdx.x;
  float* hrow = hout + (long long)v*128;
  float h0 = hrow[lane], h1 = hrow[64+lane];
  float p = fmaf(h0, Wsc[128+lane], h1*Wsc[192+lane]);
  for(int o=32;o>0;o>>=1) p += __shfl_down(p,o);
  float t = __shfl(p, 0);
  int bnode = nodes[2*v];
  t += cu[bnode] + b_sc[0];
  float alpha = sigf(t);   // TAU = 1
  hrow[lane] = alpha*h0;
  hrow[64+lane] = alpha*h1;
  if(lane==0){
    out_alpha[v] = alpha;
    out_keep[v] = 0.f;
    int ent = nodes[2*v+1];
    ca[v] = keep0[v] ? -__builtin_inff() : (alpha + ((ent>=NUSER && ent<NUSER+NITEM)?BONUS:0.f));
  }
}

// ---- candidate compaction: per-batch contiguous arrays of 64-bit keys ----
// key = (fmap(ca) << 32) | (0x7FFFFFFF - idx)  -> strictly distinct; larger = better
__global__ void k_cand_count(const int* __restrict__ nodes, const int* __restrict__ keep0,
                             int* __restrict__ ccnt, int N, int Bq){
  __shared__ int h[64];
  int tid = threadIdx.x;
  if(tid < Bq) h[tid]=0;
  __syncthreads();
  int i = blockIdx.x*256 + tid;
  if(i<N && keep0[i]==0) atomicAdd(&h[nodes[2*i]], 1);
  __syncthreads();
  if(tid<Bq && h[tid]) atomicAdd(&ccnt[tid], h[tid]);
}

__global__ void k_cand_base(const int* __restrict__ ccnt, int* __restrict__ cbase,
                            int* __restrict__ ccur, int Bq){
  if(threadIdx.x==0 && blockIdx.x==0){
    int run=0;
    for(int b=0;b<Bq;b++){ cbase[b]=run; ccur[b]=run; run+=ccnt[b]; }
    cbase[Bq]=run;
  }
}

__global__ void k_cand_fill(const int* __restrict__ nodes, const int* __restrict__ keep0,
                            const float* __restrict__ ca, int* __restrict__ ccur,
                            unsigned long long* __restrict__ cand, int N){
  int i = blockIdx.x*blockDim.x + threadIdx.x;
  if(i>=N || keep0[i]) return;
  int b = nodes[2*i];
  int p = atomicAdd(&ccur[b], 1);
  cand[p] = ((unsigned long long)fmap(ca[i])<<32) | (unsigned)(0x7FFFFFFF - i);
}

__device__ __forceinline__ int blockCountGE(const unsigned long long* __restrict__ p, int n,
                                            unsigned long long T, int tid, int* red){
  int c=0;
  for(int j=tid;j<n;j+=256) c += (p[j] >= T) ? 1 : 0;
  for(int o=32;o>0;o>>=1) c += __shfl_down(c,o);
  if((tid&63)==0) red[tid>>6]=c;
  __syncthreads();
  int r = red[0]+red[1]+red[2]+red[3];
  __syncthreads();
  return r;
}

// exact per-batch top-K over compacted distinct 64-bit keys (no tie phase needed)
__global__ __launch_bounds__(256)
void k_topk2(const unsigned long long* __restrict__ cand, const int* __restrict__ cbase,
             const int* __restrict__ idl, const int* __restrict__ nl,
             float* __restrict__ out_keep){
  if(idl[0] >= nl[0]-1) return;
  __shared__ int red[4];
  int b = blockIdx.x, tid = threadIdx.x;
  int s = cbase[b], e = cbase[b+1];
  int n = e - s;
  const unsigned long long* p = cand + s;
  if(n <= KTOP){
    for(int j=tid;j<n;j+=256){
      int idx = 0x7FFFFFFF - (int)(unsigned)(p[j] & 0xFFFFFFFFULL);
      out_keep[idx] = 1.f;
    }
    return;
  }
  unsigned long long lo = 1ULL<<63, hi = ~0ULL;
  while(hi - lo > 1ULL){
    unsigned long long mid = lo + ((hi-lo)>>1);
    int c = blockCountGE(p, n, mid, tid, red);
    if(c >= KTOP) lo = mid; else hi = mid;
  }
  // keys distinct => exactly KTOP keys >= lo
  for(int j=tid;j<n;j+=256){
    if(p[j] >= lo){
      int idx = 0x7FFFFFFF - (int)(unsigned)(p[j] & 0xFFFFFFFFULL);
      out_keep[idx] = 1.f;
    }
  }
}

__global__ void k_keepfin(const int* __restrict__ nodes, const int* __restrict__ keep0,
                          const int* __restrict__ idl, const int* __restrict__ nl,
                          float* __restrict__ out_keep, int N){
  int i = blockIdx.x*blockDim.x + threadIdx.x;
  if(i>=N) return;
  if(idl[0] < nl[0]-1){
    if(keep0[i]) out_keep[i]=1.f;
  } else {
    int ent = nodes[2*i+1];
    out_keep[i] = (ent>=NUSER && ent<NUSER+NITEM) ? 1.f : 0.f;
  }
}

extern "C" void kernel_launch(void* const* d_in, const int* in_sizes, int n_in,
                              void* d_out, int out_size, void* d_ws, size_t ws_size,
                              hipStream_t stream){
  const int*   q_sub    = (const int*)d_in[0];
  const float* hidden   = (const float*)d_in[2];
  const int*   edges    = (const int*)d_in[3];
  const int*   nodes    = (const int*)d_in[4];
  const int*   idl      = (const int*)d_in[5];
  const int*   nl       = (const int*)d_in[6];
  const int*   oni      = (const int*)d_in[7];
  const float* rel_tab  = (const float*)d_in[8];
  const float* W_i      = (const float*)d_in[9];
  const float* W_h      = (const float*)d_in[10];
  const float* b_i      = (const float*)d_in[11];
  const float* b_h      = (const float*)d_in[12];
  const float* W_pna    = (const float*)d_in[13];
  const float* b_pna    = (const float*)d_in[14];
  const float* W_sc     = (const float*)d_in[15];
  const float* b_sc     = (const float*)d_in[16];

  int Bq = in_sizes[0];
  int NP = in_sizes[2]/128;
  int E  = in_sizes[3]/6;
  int N  = in_sizes[4]/2;
  int NR = in_sizes[8]/128;
  long long nd = (long long)N*128;
  int nb = (N+255)/256;

  size_t off = 0;
  auto alloc = [&](size_t bytes)->void*{
    void* r = (char*)d_ws + off;
    off += (bytes + 255) & ~(size_t)255;
    return r;
  };
  float* agg    = (float*)alloc((size_t)CHUNK*512*4);   // 26.2 MB, reused per chunk
  float* gh_t   = (float*)alloc((size_t)NP*384*4);      // 30.7 MB
  float* gi_t   = (float*)alloc((size_t)NR*384*4);
  float* wbig   = (float*)alloc((size_t)512*384*4);
  float* hp     = (float*)alloc((size_t)NP*128*4);      // 10.2 MB
  int*   rowptr = (int*)  alloc((size_t)(N+1)*4);
  int*   cursor = (int*)  alloc((size_t)N*4);
  int*   deg_i  = (int*)  alloc((size_t)N*4);
  int*   bsum   = (int*)  alloc((size_t)nb*4);
  int*   eid    = (int*)  alloc((size_t)E*4);
  int*   inv    = (int*)  alloc((size_t)N*4);
  int*   kp0    = (int*)  alloc((size_t)N*4);
  int*   cidx   = (int*)  alloc((size_t)Bq*4);
  float* cu     = (float*)alloc((size_t)Bq*4);
  float* ca     = (float*)alloc((size_t)N*4);
  unsigned long long* cand = (unsigned long long*)alloc((size_t)N*8);  // 0.8 MB
  int*   ccnt   = (int*)  alloc((size_t)Bq*4);
  int*   cbase  = (int*)  alloc((size_t)(Bq+1)*4);
  int*   ccur   = (int*)  alloc((size_t)Bq*4);
  // total ~72.3 MB

  float* out_h = (float*)d_out;
  float* out_alpha = out_h + nd;
  float* out_keep = out_alpha + N;

  k_init<<<(N+255)/256,256,0,stream>>>(deg_i, inv, kp0, cidx, ccnt, N, Bq);
  k_small_gemm<<<(NR*384+255)/256,256,0,stream>>>(rel_tab, W_i, b_i, gi_t, NR, 384, 128);
  k_gemm<<<dim3((NP+63)/64, 384/64),256,0,stream>>>(hidden, W_h, b_h, gh_t, NP, 384, 128);
  k_wbig<<<(512*384+255)/256,256,0,stream>>>(W_pna, wbig);
  k_gemm<<<dim3((NP+63)/64, 128/64),256,0,stream>>>(hidden, W_pna + 1536*128, nullptr, hp, NP, 128, 128);
  k_scatter_old<<<(NP+255)/256,256,0,stream>>>(oni, inv, kp0, NP, N);
  k_count<<<(E+255)/256,256,0,stream>>>(edges, deg_i, E);
  k_scan1<<<nb,256,0,stream>>>(deg_i, rowptr, bsum, N);
  k_scan2<<<1,64,0,stream>>>(bsum, nb);
  k_scan3<<<(N+255)/256,256,0,stream>>>(rowptr, bsum, cursor, N, E);
  k_fill<<<(E+255)/256,256,0,stream>>>(edges, cursor, eid, E);
  for(int base=0; base<N; base+=CHUNK){
    int M = (N-base < CHUNK) ? (N-base) : CHUNK;
    k_aggcsr<<<((size_t)M*64+255)/256,256,0,stream>>>(edges, eid, rowptr, gi_t, gh_t, hidden, agg, base, M);
    k_gemm_fused<<<dim3((M+63)/64, 2),256,0,stream>>>(agg, wbig, rowptr, inv, hp, b_pna, out_h, base, M);
  }
  k_center<<<(N+255)/256,256,0,stream>>>(nodes, q_sub, cidx, N, Bq);
  k_cu<<<Bq,64,0,stream>>>(out_h, cidx, W_sc, cu, Bq);
  k_alpha<<<N,64,0,stream>>>(out_h, nodes, cu, W_sc, b_sc, kp0, out_alpha, out_keep, ca, N);
  k_cand_count<<<(N+255)/256,256,0,stream>>>(nodes, kp0, ccnt, N, Bq);
  k_cand_base<<<1,64,0,stream>>>(ccnt, cbase, ccur, Bq);
  k_cand_fill<<<(N+255)/256,256,0,stream>>>(nodes, kp0, ca, ccur, cand, N);
  k_topk2<<<Bq,256,0,stream>>>(cand, cbase, idl, nl, out_keep);
  k_keepfin<<<(N+255)/256,256,0,stream>>>(nodes, kp0, idl, nl, out_keep, N);
}

// Round 6
// 921.784 us; speedup vs baseline: 5.0488x; 1.6492x over previous
//
#include <hip/hip_runtime.h>
#include <hip/hip_bf16.h>
#include <cstdint>

#define NUSER 50000
#define NITEM 30000
#define KTOP 50
#define BONUS 0.05f
#define CHUNK 12800

typedef __attribute__((ext_vector_type(8))) short short8;
typedef __attribute__((ext_vector_type(4))) float f32x4;
typedef unsigned short u16;

__device__ __forceinline__ float sigf(float x){ return 1.0f/(1.0f + __expf(-x)); }
__device__ __forceinline__ unsigned fmap(float x){ unsigned b=__float_as_uint(x); return (b&0x80000000u)? ~b : (b|0x80000000u); }
// round-to-nearest-even f32 -> bf16 bits
__device__ __forceinline__ u16 f2bf(float x){ unsigned u=__float_as_uint(x); unsigned r=(u + 0x7FFFu + ((u>>16)&1u))>>16; return (u16)r; }
__device__ __forceinline__ float bf2f(u16 b){ return __uint_as_float(((unsigned)b)<<16); }

__global__ void k_init(int* deg_i, int* inv, int* keep0, int* cidx, int* ccnt, int N, int Bq){
  int i = blockIdx.x*blockDim.x + threadIdx.x;
  if(i < N){ deg_i[i]=0; inv[i]=-1; keep0[i]=0; }
  if(i < Bq){ cidx[i]=0x7FFFFFFF; ccnt[i]=0; }
}

// tiny GEMM (thread per output) for gi_table (27x384)
__global__ void k_small_gemm(const float* __restrict__ A, const float* __restrict__ W,
                             const float* __restrict__ bias, float* __restrict__ C,
                             int M, int Nn, int Kk){
  int i = blockIdx.x*blockDim.x + threadIdx.x;
  if(i >= M*Nn) return;
  int r = i/Nn, c = i - r*Nn;
  float acc = bias ? bias[c] : 0.f;
  for(int k=0;k<Kk;k++) acc = fmaf(A[r*Kk+k], W[k*Nn+c], acc);
  C[i] = acc;
}

// repack W_pna rows [0:1536] transposed into split-bf16: wbigT[c][k], c=0..383 (c=slice*128+j), k=0..511
__global__ void k_wbigT(const float* __restrict__ Wp, u16* __restrict__ Thi, u16* __restrict__ Tlo){
  int i = blockIdx.x*blockDim.x + threadIdx.x;
  if(i >= 384*512) return;
  int c = i>>9, k = i&511;
  float v = Wp[((c>>7)*512 + k)*128 + (c&127)];
  u16 h = f2bf(v);
  Thi[i] = h;
  Tlo[i] = f2bf(v - bf2f(h));
}

// f32 tiled GEMM: C[MxN] = A[MxK] @ B[KxN] (+bias per col), A row-major
__global__ __launch_bounds__(256)
void k_gemm(const float* __restrict__ A, const float* __restrict__ Bm,
            const float* __restrict__ bias, float* __restrict__ C,
            int M, int Nn, int Kk){
  __shared__ float As[32][68];
  __shared__ float Bs[32][64];
  int tid = threadIdx.x;
  int tx = tid & 15, ty = tid >> 4;
  int bm = blockIdx.x*64, bn = blockIdx.y*64;
  float acc[4][4] = {};
  for(int k0=0;k0<Kk;k0+=32){
    #pragma unroll
    for(int l=0;l<8;l++){
      int li = tid + l*256;
      int c = li & 31, r = li >> 5;
      int row = bm + r;
      float v = 0.f;
      if(row < M) v = A[(long long)row*Kk + k0 + c];
      As[c][r] = v;
    }
    #pragma unroll
    for(int l=0;l<8;l++){
      int li = tid + l*256;
      int j = li & 63, c = li >> 6;
      Bs[c][j] = Bm[(long long)(k0+c)*Nn + bn + j];
    }
    __syncthreads();
    #pragma unroll
    for(int k=0;k<32;k++){
      float4 a4 = *(const float4*)&As[k][ty*4];
      float4 b4 = *(const float4*)&Bs[k][tx*4];
      float av[4]={a4.x,a4.y,a4.z,a4.w};
      float bv[4]={b4.x,b4.y,b4.z,b4.w};
      #pragma unroll
      for(int ii=0;ii<4;ii++)
        #pragma unroll
        for(int jj=0;jj<4;jj++)
          acc[ii][jj] = fmaf(av[ii], bv[jj], acc[ii][jj]);
    }
    __syncthreads();
  }
  #pragma unroll
  for(int ii=0;ii<4;ii++){
    int row = bm + ty*4 + ii;
    if(row >= M) continue;
    float4 o;
    o.x=acc[ii][0]; o.y=acc[ii][1]; o.z=acc[ii][2]; o.w=acc[ii][3];
    if(bias){ int cb = bn + tx*4; o.x+=bias[cb]; o.y+=bias[cb+1]; o.z+=bias[cb+2]; o.w+=bias[cb+3]; }
    *(float4*)&C[(long long)row*Nn + bn + tx*4] = o;
  }
}

__global__ void k_scatter_old(const int* __restrict__ oni, int* __restrict__ inv,
                              int* __restrict__ keep0, int NP, int N){
  int i = blockIdx.x*blockDim.x + threadIdx.x;
  if(i>=NP) return;
  int v = oni[i];
  if(v>=0 && v<N){ inv[v]=i; keep0[v]=1; }
}

// ---- CSR build ----
__global__ void k_count(const int* __restrict__ edges, int* __restrict__ deg_i, int E){
  int e = blockIdx.x*blockDim.x + threadIdx.x;
  if(e<E) atomicAdd(&deg_i[edges[(long long)e*6+5]], 1);
}

__global__ __launch_bounds__(256)
void k_scan1(const int* __restrict__ deg_i, int* __restrict__ rowptr, int* __restrict__ bsum, int N){
  __shared__ int sc[256];
  int tid=threadIdx.x; int i = blockIdx.x*256+tid;
  int v = (i<N)? deg_i[i] : 0;
  sc[tid]=v; __syncthreads();
  for(int off=1; off<256; off<<=1){
    int t = (tid>=off)? sc[tid-off] : 0;
    __syncthreads();
    sc[tid] += t;
    __syncthreads();
  }
  if(i<N) rowptr[i] = sc[tid] - v;
  if(tid==255) bsum[blockIdx.x] = sc[255];
}

__global__ void k_scan2(int* bsum, int nb){
  if(threadIdx.x==0 && blockIdx.x==0){
    int run=0;
    for(int j=0;j<nb;j++){ int t=bsum[j]; bsum[j]=run; run+=t; }
  }
}

__global__ void k_scan3(int* __restrict__ rowptr, const int* __restrict__ bsum,
                        int* __restrict__ cursor, int N, int E){
  int i = blockIdx.x*blockDim.x + threadIdx.x;
  if(i<N){ int r = rowptr[i] + bsum[i>>8]; rowptr[i]=r; cursor[i]=r; }
  if(i==0) rowptr[N]=E;
}

__global__ void k_fill(const int* __restrict__ edges, int* __restrict__ cursor,
                       int* __restrict__ eid, int E){
  int e = blockIdx.x*blockDim.x + threadIdx.x;
  if(e<E){ int obj = edges[(long long)e*6+5]; int p = atomicAdd(&cursor[obj],1); eid[p]=e; }
}

// ---- per-node aggregation (one wave per node), writes split-bf16 agg planes [CHUNK x 512] ----
__global__ __launch_bounds__(256)
void k_aggcsr(const int* __restrict__ edges, const int* __restrict__ eid,
              const int* __restrict__ rowptr, const float* __restrict__ gi_t,
              const float* __restrict__ gh_t, const float* __restrict__ hidden,
              u16* __restrict__ ahi, u16* __restrict__ alo, int base, int M){
  int wid = (blockIdx.x*256 + threadIdx.x)>>6;
  int lane = threadIdx.x & 63;
  if(wid >= M) return;
  int v = base + wid;
  int r0 = rowptr[v], r1 = rowptr[v+1];
  float s0=0.f, q0=0.f, s1v=0.f, q1=0.f;
  float mn0=INFINITY, mx0=-INFINITY, mn1=INFINITY, mx1=-INFINITY;
  for(int j=r0;j<r1;++j){
    int e = eid[j];
    const int* er = edges + (long long)e*6;
    int sub = er[4], rel = er[2];
    const float* gi = gi_t + (long long)rel*384;
    const float* gh = gh_t + (long long)sub*384;
    const float* hs = hidden + (long long)sub*128;
    {
      int d = lane;
      float r = sigf(gi[d]+gh[d]);
      float z = sigf(gi[128+d]+gh[128+d]);
      float n = tanhf(gi[256+d] + r*gh[256+d]);
      float m = (1.f-z)*n + z*hs[d];
      s0+=m; q0=fmaf(m,m,q0); mn0=fminf(mn0,m); mx0=fmaxf(mx0,m);
    }
    {
      int d = lane+64;
      float r = sigf(gi[d]+gh[d]);
      float z = sigf(gi[128+d]+gh[128+d]);
      float n = tanhf(gi[256+d] + r*gh[256+d]);
      float m = (1.f-z)*n + z*hs[d];
      s1v+=m; q1=fmaf(m,m,q1); mn1=fminf(mn1,m); mx1=fmaxf(mx1,m);
    }
  }
  float dg = (float)(r1-r0);
  float dc = fmaxf(dg, 1.f);
  bool has = dg > 0.f;
  u16* ah = ahi + (long long)wid*512;
  u16* al = alo + (long long)wid*512;
  auto put = [&](int idx, float val){
    u16 h = f2bf(val); ah[idx]=h; al[idx]=f2bf(val - bf2f(h));
  };
  {
    float mean = s0/dc;
    float var = q0/dc - mean*mean;
    float sd = sqrtf(fmaxf(var,0.f)+1e-5f);
    put(lane, mean); put(128+lane, sd);
    put(256+lane, has? mn0:0.f); put(384+lane, has? mx0:0.f);
  }
  {
    float mean = s1v/dc;
    float var = q1/dc - mean*mean;
    float sd = sqrtf(fmaxf(var,0.f)+1e-5f);
    put(64+lane, mean); put(192+lane, sd);
    put(320+lane, has? mn1:0.f); put(448+lane, has? mx1:0.f);
  }
}

// ---- fused PNA GEMM via split-bf16 MFMA (3-pass): hout[v] = acc0 + logd*acc1 + att*acc2 + b_pna + hp[inv[v]] ----
// A: [CHUNK x 512] hi/lo bf16. W: wbigT [384 x 512] hi/lo bf16 (col-major of original).
// block: 256 thr (4 waves 2x2), tile M=64 x Ncols=64, 3 slices per block.
__global__ __launch_bounds__(256)
void k_mfma_fused(const u16* __restrict__ ahi, const u16* __restrict__ alo,
                  const u16* __restrict__ whi, const u16* __restrict__ wlo,
                  const int* __restrict__ rowptr, const int* __restrict__ inv,
                  const float* __restrict__ hp, const float* __restrict__ b_pna,
                  float* __restrict__ hout, int base, int M){
  __shared__ u16 As_hi[64][40];
  __shared__ u16 As_lo[64][40];
  __shared__ u16 Ws_hi[3][64][40];
  __shared__ u16 Ws_lo[3][64][40];
  int tid = threadIdx.x;
  int l = tid & 63;
  int wv = tid >> 6;
  int wm = wv >> 1, wn = wv & 1;
  int kg = l >> 4, lr = l & 15;
  int bm = blockIdx.x*64, bn = blockIdx.y*64;
  f32x4 acc[3][2][2] = {};
  int sr = tid >> 2;          // 0..63 (row/col for staging)
  int seg = tid & 3;          // 0..3 (16B segment)
  for(int k0=0; k0<512; k0+=32){
    // stage A (hi/lo): rows bm..bm+63, k0..k0+31
    {
      const short8 vh = *(const short8*)(ahi + (long long)(bm+sr)*512 + k0 + seg*8);
      const short8 vl = *(const short8*)(alo + (long long)(bm+sr)*512 + k0 + seg*8);
      *(short8*)&As_hi[sr][seg*8] = vh;
      *(short8*)&As_lo[sr][seg*8] = vl;
    }
    // stage W: 3 slices, cols (s*128+bn+sr), k0..k0+31
    #pragma unroll
    for(int s=0;s<3;s++){
      const short8 vh = *(const short8*)(whi + (long long)(s*128+bn+sr)*512 + k0 + seg*8);
      const short8 vl = *(const short8*)(wlo + (long long)(s*128+bn+sr)*512 + k0 + seg*8);
      *(short8*)&Ws_hi[s][sr][seg*8] = vh;
      *(short8*)&Ws_lo[s][sr][seg*8] = vl;
    }
    __syncthreads();
    short8 ah[2], al[2];
    #pragma unroll
    for(int mi=0;mi<2;mi++){
      ah[mi] = *(const short8*)&As_hi[wm*32+mi*16+lr][kg*8];
      al[mi] = *(const short8*)&As_lo[wm*32+mi*16+lr][kg*8];
    }
    #pragma unroll
    for(int s=0;s<3;s++){
      #pragma unroll
      for(int ni=0;ni<2;ni++){
        short8 bh = *(const short8*)&Ws_hi[s][wn*32+ni*16+lr][kg*8];
        short8 bl = *(const short8*)&Ws_lo[s][wn*32+ni*16+lr][kg*8];
        #pragma unroll
        for(int mi=0;mi<2;mi++){
          acc[s][mi][ni] = __builtin_amdgcn_mfma_f32_16x16x32_bf16(ah[mi], bh, acc[s][mi][ni], 0,0,0);
          acc[s][mi][ni] = __builtin_amdgcn_mfma_f32_16x16x32_bf16(al[mi], bh, acc[s][mi][ni], 0,0,0);
          acc[s][mi][ni] = __builtin_amdgcn_mfma_f32_16x16x32_bf16(ah[mi], bl, acc[s][mi][ni], 0,0,0);
        }
      }
    }
    __syncthreads();
  }
  // epilogue: C/D layout: col = lr, row = kg*4 + reg (within 16x16 frag)
  #pragma unroll
  for(int mi=0;mi<2;mi++){
    #pragma unroll
    for(int reg=0;reg<4;reg++){
      int rl = bm + wm*32 + mi*16 + kg*4 + reg;
      if(rl >= M) continue;
      int v = base + rl;
      int d0 = rowptr[v], d1 = rowptr[v+1];
      float logd = log1pf((float)(d1-d0));
      float att = 1.0f/(logd + 1.0f);
      int iv = inv[v];
      #pragma unroll
      for(int ni=0;ni<2;ni++){
        int col = bn + wn*32 + ni*16 + lr;
        float o = acc[0][mi][ni][reg] + logd*acc[1][mi][ni][reg] + att*acc[2][mi][ni][reg] + b_pna[col];
        if(iv>=0) o += hp[(long long)iv*128 + col];
        hout[(long long)v*128 + col] = o;
      }
    }
  }
}

__global__ void k_center(const int* __restrict__ nodes, const int* __restrict__ q_sub,
                         int* __restrict__ cidx, int N, int Bq){
  int i = blockIdx.x*blockDim.x + threadIdx.x;
  if(i>=N) return;
  int b = nodes[2*i];
  if(b>=0 && b<Bq && nodes[2*i+1]==q_sub[b]) atomicMin((unsigned*)&cidx[b], (unsigned)i);
}

__global__ __launch_bounds__(64)
void k_cu(const float* __restrict__ hout, const int* __restrict__ cidx,
          const float* __restrict__ Wsc, float* __restrict__ cu, int Bq){
  int b = blockIdx.x, lane = threadIdx.x;
  int i = cidx[b]; if(i==0x7FFFFFFF) i=0;
  const float* hrow = hout + (long long)i*128;
  float p = fmaf(hrow[lane], Wsc[lane], hrow[64+lane]*Wsc[64+lane]);
  for(int o=32;o>0;o>>=1) p += __shfl_down(p, o);
  if(lane==0) cu[b]=p;
}

__global__ __launch_bounds__(256)
void k_alpha(float* __restrict__ hout, const int* __restrict__ nodes,
             const float* __restrict__ cu, const float* __restrict__ Wsc,
             const float* __restrict__ b_sc, const int* __restrict__ keep0,
             float* __restrict__ out_alpha, float* __restrict__ out_keep,
             float* __restrict__ ca, int N){
  int v = blockIdx.x*4 + (threadIdx.x>>6);
  int lane = threadIdx.x & 63;
  if(v>=N) return;
  float* hrow = hout + (long long)v*128;
  float h0 = hrow[lane], h1 = hrow[64+lane];
  float p = fmaf(h0, Wsc[128+lane], h1*Wsc[192+lane]);
  for(int o=32;o>0;o>>=1) p += __shfl_down(p,o);
  float t = __shfl(p, 0);
  int bnode = nodes[2*v];
  t += cu[bnode] + b_sc[0];
  float alpha = sigf(t);   // TAU = 1
  hrow[lane] = alpha*h0;
  hrow[64+lane] = alpha*h1;
  if(lane==0){
    out_alpha[v] = alpha;
    out_keep[v] = 0.f;
    int ent = nodes[2*v+1];
    ca[v] = keep0[v] ? -__builtin_inff() : (alpha + ((ent>=NUSER && ent<NUSER+NITEM)?BONUS:0.f));
  }
}

// ---- candidate compaction ----
__global__ void k_cand_count(const int* __restrict__ nodes, const int* __restrict__ keep0,
                             int* __restrict__ ccnt, int N, int Bq){
  __shared__ int h[64];
  int tid = threadIdx.x;
  if(tid < Bq) h[tid]=0;
  __syncthreads();
  int i = blockIdx.x*256 + tid;
  if(i<N && keep0[i]==0) atomicAdd(&h[nodes[2*i]], 1);
  __syncthreads();
  if(tid<Bq && h[tid]) atomicAdd(&ccnt[tid], h[tid]);
}

__global__ void k_cand_base(const int* __restrict__ ccnt, int* __restrict__ cbase,
                            int* __restrict__ ccur, int Bq){
  if(threadIdx.x==0 && blockIdx.x==0){
    int run=0;
    for(int b=0;b<Bq;b++){ cbase[b]=run; ccur[b]=run; run+=ccnt[b]; }
    cbase[Bq]=run;
  }
}

// low-contention fill: LDS hist + one global atomic per (block,batch)
__global__ __launch_bounds__(256)
void k_cand_fill(const int* __restrict__ nodes, const int* __restrict__ keep0,
                 const float* __restrict__ ca, int* __restrict__ ccur,
                 unsigned long long* __restrict__ cand, int N, int Bq){
  __shared__ int h[64];
  __shared__ int basep[64];
  int tid = threadIdx.x;
  if(tid < Bq) h[tid]=0;
  __syncthreads();
  int i = blockIdx.x*256 + tid;
  bool valid = (i<N) && (keep0[i]==0);
  int b = 0, myofs = 0;
  if(valid){ b = nodes[2*i]; myofs = atomicAdd(&h[b], 1); }
  __syncthreads();
  if(tid < Bq && h[tid]) basep[tid] = atomicAdd(&ccur[tid], h[tid]);
  __syncthreads();
  if(valid){
    cand[basep[b] + myofs] = ((unsigned long long)fmap(ca[i])<<32) | (unsigned)(0x7FFFFFFF - i);
  }
}

__device__ __forceinline__ int blockCountGE(const unsigned long long* __restrict__ p, int n,
                                            unsigned long long T, int tid, int* red){
  int c=0;
  for(int j=tid;j<n;j+=256) c += (p[j] >= T) ? 1 : 0;
  for(int o=32;o>0;o>>=1) c += __shfl_down(c,o);
  if((tid&63)==0) red[tid>>6]=c;
  __syncthreads();
  int r = red[0]+red[1]+red[2]+red[3];
  __syncthreads();
  return r;
}

__global__ __launch_bounds__(256)
void k_topk2(const unsigned long long* __restrict__ cand, const int* __restrict__ cbase,
             const int* __restrict__ idl, const int* __restrict__ nl,
             float* __restrict__ out_keep){
  if(idl[0] >= nl[0]-1) return;
  __shared__ int red[4];
  int b = blockIdx.x, tid = threadIdx.x;
  int s = cbase[b], e = cbase[b+1];
  int n = e - s;
  const unsigned long long* p = cand + s;
  if(n <= KTOP){
    for(int j=tid;j<n;j+=256){
      int idx = 0x7FFFFFFF - (int)(unsigned)(p[j] & 0xFFFFFFFFULL);
      out_keep[idx] = 1.f;
    }
    return;
  }
  unsigned long long lo = 1ULL<<63, hi = ~0ULL;
  while(hi - lo > 1ULL){
    unsigned long long mid = lo + ((hi-lo)>>1);
    int c = blockCountGE(p, n, mid, tid, red);
    if(c >= KTOP) lo = mid; else hi = mid;
  }
  for(int j=tid;j<n;j+=256){
    if(p[j] >= lo){
      int idx = 0x7FFFFFFF - (int)(unsigned)(p[j] & 0xFFFFFFFFULL);
      out_keep[idx] = 1.f;
    }
  }
}

__global__ void k_keepfin(const int* __restrict__ nodes, const int* __restrict__ keep0,
                          const int* __restrict__ idl, const int* __restrict__ nl,
                          float* __restrict__ out_keep, int N){
  int i = blockIdx.x*blockDim.x + threadIdx.x;
  if(i>=N) return;
  if(idl[0] < nl[0]-1){
    if(keep0[i]) out_keep[i]=1.f;
  } else {
    int ent = nodes[2*i+1];
    out_keep[i] = (ent>=NUSER && ent<NUSER+NITEM) ? 1.f : 0.f;
  }
}

extern "C" void kernel_launch(void* const* d_in, const int* in_sizes, int n_in,
                              void* d_out, int out_size, void* d_ws, size_t ws_size,
                              hipStream_t stream){
  const int*   q_sub    = (const int*)d_in[0];
  const float* hidden   = (const float*)d_in[2];
  const int*   edges    = (const int*)d_in[3];
  const int*   nodes    = (const int*)d_in[4];
  const int*   idl      = (const int*)d_in[5];
  const int*   nl       = (const int*)d_in[6];
  const int*   oni      = (const int*)d_in[7];
  const float* rel_tab  = (const float*)d_in[8];
  const float* W_i      = (const float*)d_in[9];
  const float* W_h      = (const float*)d_in[10];
  const float* b_i      = (const float*)d_in[11];
  const float* b_h      = (const float*)d_in[12];
  const float* W_pna    = (const float*)d_in[13];
  const float* b_pna    = (const float*)d_in[14];
  const float* W_sc     = (const float*)d_in[15];
  const float* b_sc     = (const float*)d_in[16];

  int Bq = in_sizes[0];
  int NP = in_sizes[2]/128;
  int E  = in_sizes[3]/6;
  int N  = in_sizes[4]/2;
  int NR = in_sizes[8]/128;
  long long nd = (long long)N*128;
  int nb = (N+255)/256;

  size_t off = 0;
  auto alloc = [&](size_t bytes)->void*{
    void* r = (char*)d_ws + off;
    off += (bytes + 255) & ~(size_t)255;
    return r;
  };
  u16*   ahi    = (u16*)  alloc((size_t)CHUNK*512*2);   // 13.1 MB
  u16*   alo    = (u16*)  alloc((size_t)CHUNK*512*2);   // 13.1 MB
  float* gh_t   = (float*)alloc((size_t)NP*384*4);      // 30.7 MB
  float* gi_t   = (float*)alloc((size_t)NR*384*4);
  u16*   whi    = (u16*)  alloc((size_t)384*512*2);
  u16*   wlo    = (u16*)  alloc((size_t)384*512*2);
  float* hp     = (float*)alloc((size_t)NP*128*4);      // 10.2 MB
  int*   rowptr = (int*)  alloc((size_t)(N+1)*4);
  int*   cursor = (int*)  alloc((size_t)N*4);
  int*   deg_i  = (int*)  alloc((size_t)N*4);
  int*   bsum   = (int*)  alloc((size_t)nb*4);
  int*   eid    = (int*)  alloc((size_t)E*4);
  int*   inv    = (int*)  alloc((size_t)N*4);
  int*   kp0    = (int*)  alloc((size_t)N*4);
  int*   cidx   = (int*)  alloc((size_t)Bq*4);
  float* cu     = (float*)alloc((size_t)Bq*4);
  float* ca     = (float*)alloc((size_t)N*4);
  unsigned long long* cand = (unsigned long long*)alloc((size_t)N*8);
  int*   ccnt   = (int*)  alloc((size_t)Bq*4);
  int*   cbase  = (int*)  alloc((size_t)(Bq+1)*4);
  int*   ccur   = (int*)  alloc((size_t)Bq*4);
  // total ~76 MB

  float* out_h = (float*)d_out;
  float* out_alpha = out_h + nd;
  float* out_keep = out_alpha + N;

  k_init<<<(N+255)/256,256,0,stream>>>(deg_i, inv, kp0, cidx, ccnt, N, Bq);
  k_small_gemm<<<(NR*384+255)/256,256,0,stream>>>(rel_tab, W_i, b_i, gi_t, NR, 384, 128);
  k_gemm<<<dim3((NP+63)/64, 384/64),256,0,stream>>>(hidden, W_h, b_h, gh_t, NP, 384, 128);
  k_wbigT<<<(384*512+255)/256,256,0,stream>>>(W_pna, whi, wlo);
  k_gemm<<<dim3((NP+63)/64, 128/64),256,0,stream>>>(hidden, W_pna + 1536*128, nullptr, hp, NP, 128, 128);
  k_scatter_old<<<(NP+255)/256,256,0,stream>>>(oni, inv, kp0, NP, N);
  k_count<<<(E+255)/256,256,0,stream>>>(edges, deg_i, E);
  k_scan1<<<nb,256,0,stream>>>(deg_i, rowptr, bsum, N);
  k_scan2<<<1,64,0,stream>>>(bsum, nb);
  k_scan3<<<(N+255)/256,256,0,stream>>>(rowptr, bsum, cursor, N, E);
  k_fill<<<(E+255)/256,256,0,stream>>>(edges, cursor, eid, E);
  for(int base=0; base<N; base+=CHUNK){
    int M = (N-base < CHUNK) ? (N-base) : CHUNK;
    k_aggcsr<<<((size_t)M*64+255)/256,256,0,stream>>>(edges, eid, rowptr, gi_t, gh_t, hidden, ahi, alo, base, M);
    k_mfma_fused<<<dim3((M+63)/64, 2),256,0,stream>>>(ahi, alo, whi, wlo, rowptr, inv, hp, b_pna, out_h, base, M);
  }
  k_center<<<(N+255)/256,256,0,stream>>>(nodes, q_sub, cidx, N, Bq);
  k_cu<<<Bq,64,0,stream>>>(out_h, cidx, W_sc, cu, Bq);
  k_alpha<<<(N+3)/4,256,0,stream>>>(out_h, nodes, cu, W_sc, b_sc, kp0, out_alpha, out_keep, ca, N);
  k_cand_count<<<(N+255)/256,256,0,stream>>>(nodes, kp0, ccnt, N, Bq);
  k_cand_base<<<1,64,0,stream>>>(ccnt, cbase, ccur, Bq);
  k_cand_fill<<<(N+255)/256,256,0,stream>>>(nodes, kp0, ca, ccur, cand, N, Bq);
  k_topk2<<<Bq,256,0,stream>>>(cand, cbase, idl, nl, out_keep);
  k_keepfin<<<(N+255)/256,256,0,stream>>>(nodes, kp0, idl, nl, out_keep, N);
}

// Round 7
// 650.296 us; speedup vs baseline: 7.1566x; 1.4175x over previous
//
#include <hip/hip_runtime.h>
#include <hip/hip_bf16.h>
#include <cstdint>

#define NUSER 50000
#define NITEM 30000
#define KTOP 50
#define BONUS 0.05f

typedef __attribute__((ext_vector_type(8))) short short8;
typedef __attribute__((ext_vector_type(4))) float f32x4;
typedef unsigned short u16;

__device__ __forceinline__ float sigf(float x){ return 1.0f/(1.0f + __expf(-x)); }
__device__ __forceinline__ unsigned fmap(float x){ unsigned b=__float_as_uint(x); return (b&0x80000000u)? ~b : (b|0x80000000u); }
// round-to-nearest-even f32 -> bf16 bits
__device__ __forceinline__ u16 f2bf(float x){ unsigned u=__float_as_uint(x); unsigned r=(u + 0x7FFFu + ((u>>16)&1u))>>16; return (u16)r; }
__device__ __forceinline__ float bf2f(u16 b){ return __uint_as_float(((unsigned)b)<<16); }

__global__ void k_init(int* deg_i, int* inv, int* keep0, int* cidx, int* ccnt, int N, int Bq){
  int i = blockIdx.x*blockDim.x + threadIdx.x;
  if(i < N){ deg_i[i]=0; inv[i]=-1; keep0[i]=0; }
  if(i < Bq){ cidx[i]=0x7FFFFFFF; ccnt[i]=0; }
}

// tiny GEMM (thread per output) for gi_table (27x384)
__global__ void k_small_gemm(const float* __restrict__ A, const float* __restrict__ W,
                             const float* __restrict__ bias, float* __restrict__ C,
                             int M, int Nn, int Kk){
  int i = blockIdx.x*blockDim.x + threadIdx.x;
  if(i >= M*Nn) return;
  int r = i/Nn, c = i - r*Nn;
  float acc = bias ? bias[c] : 0.f;
  for(int k=0;k<Kk;k++) acc = fmaf(A[r*Kk+k], W[k*Nn+c], acc);
  C[i] = acc;
}

// weight prep: split-bf16 transposed tables
//  [0, 196608): wbigT[c][k] c<384,k<512 = W_pna[((c>>7)*512+k)*128 + (c&127)]
//  [196608, 245760): whT[c][k] c<384,k<128 = W_h[k*384+c]
//  [245760, 262144): w4T[c][k] c<128,k<128 = W_pna[(1536+k)*128+c]
__global__ void k_prep(const float* __restrict__ Wp, const float* __restrict__ Wh,
                       u16* __restrict__ wbig_hi, u16* __restrict__ wbig_lo,
                       u16* __restrict__ whT_hi, u16* __restrict__ whT_lo,
                       u16* __restrict__ w4T_hi, u16* __restrict__ w4T_lo){
  int i = blockIdx.x*blockDim.x + threadIdx.x;
  if(i >= 262144) return;
  float v; u16* ph; u16* pl; int j;
  if(i < 196608){
    int c = i>>9, k = i&511;
    v = Wp[((c>>7)*512 + k)*128 + (c&127)];
    ph = wbig_hi; pl = wbig_lo; j = i;
  } else if(i < 245760){
    j = i - 196608;
    int c = j>>7, k = j&127;
    v = Wh[k*384 + c];
    ph = whT_hi; pl = whT_lo;
  } else {
    j = i - 245760;
    int c = j>>7, k = j&127;
    v = Wp[(1536 + k)*128 + c];
    ph = w4T_hi; pl = w4T_lo;
  }
  u16 h = f2bf(v);
  ph[j] = h;
  pl[j] = f2bf(v - bf2f(h));
}

// split hidden [NP x 128] into hi/lo bf16
__global__ void k_split_h(const float* __restrict__ hidden, u16* __restrict__ hhi,
                          u16* __restrict__ hlo, int n){
  int i = blockIdx.x*blockDim.x + threadIdx.x;
  if(i>=n) return;
  float v = hidden[i];
  u16 h = f2bf(v);
  hhi[i]=h; hlo[i]=f2bf(v - bf2f(h));
}

// generic split-bf16 MFMA GEMM (3-pass): C[M x Nn] = A[M x K] @ WT[Nn x K]^T (+bias)
__global__ __launch_bounds__(256)
void k_mfma_ab(const u16* __restrict__ Ahi, const u16* __restrict__ Alo,
               const u16* __restrict__ WThi, const u16* __restrict__ WTlo,
               const float* __restrict__ bias, float* __restrict__ C,
               int M, int Nn, int K){
  __shared__ u16 As_hi[64][40];
  __shared__ u16 As_lo[64][40];
  __shared__ u16 Ws_hi[64][40];
  __shared__ u16 Ws_lo[64][40];
  int tid = threadIdx.x;
  int l = tid & 63, wv = tid >> 6;
  int wm = wv >> 1, wn = wv & 1;
  int kg = l >> 4, lr = l & 15;
  int bm = blockIdx.x*64, bn = blockIdx.y*64;
  f32x4 acc[2][2] = {};
  int sr = tid >> 2, seg = tid & 3;
  for(int k0=0; k0<K; k0+=32){
    *(short8*)&As_hi[sr][seg*8] = *(const short8*)(Ahi + (long long)(bm+sr)*K + k0 + seg*8);
    *(short8*)&As_lo[sr][seg*8] = *(const short8*)(Alo + (long long)(bm+sr)*K + k0 + seg*8);
    *(short8*)&Ws_hi[sr][seg*8] = *(const short8*)(WThi + (long long)(bn+sr)*K + k0 + seg*8);
    *(short8*)&Ws_lo[sr][seg*8] = *(const short8*)(WTlo + (long long)(bn+sr)*K + k0 + seg*8);
    __syncthreads();
    short8 ah[2], al[2], bh[2], bl[2];
    #pragma unroll
    for(int mi=0;mi<2;mi++){
      ah[mi] = *(const short8*)&As_hi[wm*32+mi*16+lr][kg*8];
      al[mi] = *(const short8*)&As_lo[wm*32+mi*16+lr][kg*8];
    }
    #pragma unroll
    for(int ni=0;ni<2;ni++){
      bh[ni] = *(const short8*)&Ws_hi[wn*32+ni*16+lr][kg*8];
      bl[ni] = *(const short8*)&Ws_lo[wn*32+ni*16+lr][kg*8];
    }
    #pragma unroll
    for(int ni=0;ni<2;ni++)
      #pragma unroll
      for(int mi=0;mi<2;mi++){
        acc[mi][ni] = __builtin_amdgcn_mfma_f32_16x16x32_bf16(ah[mi], bh[ni], acc[mi][ni], 0,0,0);
        acc[mi][ni] = __builtin_amdgcn_mfma_f32_16x16x32_bf16(al[mi], bh[ni], acc[mi][ni], 0,0,0);
        acc[mi][ni] = __builtin_amdgcn_mfma_f32_16x16x32_bf16(ah[mi], bl[ni], acc[mi][ni], 0,0,0);
      }
    __syncthreads();
  }
  #pragma unroll
  for(int mi=0;mi<2;mi++)
    #pragma unroll
    for(int reg=0;reg<4;reg++){
      int row = bm + wm*32 + mi*16 + kg*4 + reg;
      if(row >= M) continue;
      #pragma unroll
      for(int ni=0;ni<2;ni++){
        int col = bn + wn*32 + ni*16 + lr;
        float o = acc[mi][ni][reg];
        if(bias) o += bias[col];
        C[(long long)row*Nn + col] = o;
      }
    }
}

__global__ void k_scatter_old(const int* __restrict__ oni, int* __restrict__ inv,
                              int* __restrict__ keep0, int NP, int N){
  int i = blockIdx.x*blockDim.x + threadIdx.x;
  if(i>=NP) return;
  int v = oni[i];
  if(v>=0 && v<N){ inv[v]=i; keep0[v]=1; }
}

// ---- CSR build ----
__global__ void k_count(const int* __restrict__ edges, int* __restrict__ deg_i, int E){
  int e = blockIdx.x*blockDim.x + threadIdx.x;
  if(e<E) atomicAdd(&deg_i[edges[(long long)e*6+5]], 1);
}

__global__ __launch_bounds__(256)
void k_scan1(const int* __restrict__ deg_i, int* __restrict__ rowptr, int* __restrict__ bsum, int N){
  __shared__ int sc[256];
  int tid=threadIdx.x; int i = blockIdx.x*256+tid;
  int v = (i<N)? deg_i[i] : 0;
  sc[tid]=v; __syncthreads();
  for(int off=1; off<256; off<<=1){
    int t = (tid>=off)? sc[tid-off] : 0;
    __syncthreads();
    sc[tid] += t;
    __syncthreads();
  }
  if(i<N) rowptr[i] = sc[tid] - v;
  if(tid==255) bsum[blockIdx.x] = sc[255];
}

// parallel exclusive scan of block sums (nb <= 512)
__global__ __launch_bounds__(512)
void k_scan2(int* __restrict__ bsum, int nb){
  __shared__ int sc[512];
  int tid = threadIdx.x;
  int v = (tid<nb)? bsum[tid] : 0;
  sc[tid]=v; __syncthreads();
  for(int off=1; off<512; off<<=1){
    int t = (tid>=off)? sc[tid-off] : 0;
    __syncthreads();
    sc[tid] += t;
    __syncthreads();
  }
  if(tid<nb) bsum[tid] = sc[tid] - v;
}

__global__ void k_scan3(int* __restrict__ rowptr, const int* __restrict__ bsum,
                        int* __restrict__ cursor, int N, int E){
  int i = blockIdx.x*blockDim.x + threadIdx.x;
  if(i<N){ int r = rowptr[i] + bsum[i>>8]; rowptr[i]=r; cursor[i]=r; }
  if(i==0) rowptr[N]=E;
}

__global__ void k_fill(const int* __restrict__ edges, int* __restrict__ cursor,
                       int* __restrict__ eid, int E){
  int e = blockIdx.x*blockDim.x + threadIdx.x;
  if(e<E){ int obj = edges[(long long)e*6+5]; int p = atomicAdd(&cursor[obj],1); eid[p]=e; }
}

// ---- per-node aggregation (one wave per node), writes split-bf16 agg planes ----
__global__ __launch_bounds__(256)
void k_aggcsr(const int* __restrict__ edges, const int* __restrict__ eid,
              const int* __restrict__ rowptr, const float* __restrict__ gi_t,
              const float* __restrict__ gh_t, const float* __restrict__ hidden,
              u16* __restrict__ ahi, u16* __restrict__ alo, int base, int M){
  int wid = (blockIdx.x*256 + threadIdx.x)>>6;
  int lane = threadIdx.x & 63;
  if(wid >= M) return;
  int v = base + wid;
  int r0 = rowptr[v], r1 = rowptr[v+1];
  float s0=0.f, q0=0.f, s1v=0.f, q1=0.f;
  float mn0=INFINITY, mx0=-INFINITY, mn1=INFINITY, mx1=-INFINITY;
  for(int j=r0;j<r1;++j){
    int e = eid[j];
    const int* er = edges + (long long)e*6;
    int sub = er[4], rel = er[2];
    const float* gi = gi_t + (long long)rel*384;
    const float* gh = gh_t + (long long)sub*384;
    const float* hs = hidden + (long long)sub*128;
    {
      int d = lane;
      float r = sigf(gi[d]+gh[d]);
      float z = sigf(gi[128+d]+gh[128+d]);
      float n = tanhf(gi[256+d] + r*gh[256+d]);
      float m = (1.f-z)*n + z*hs[d];
      s0+=m; q0=fmaf(m,m,q0); mn0=fminf(mn0,m); mx0=fmaxf(mx0,m);
    }
    {
      int d = lane+64;
      float r = sigf(gi[d]+gh[d]);
      float z = sigf(gi[128+d]+gh[128+d]);
      float n = tanhf(gi[256+d] + r*gh[256+d]);
      float m = (1.f-z)*n + z*hs[d];
      s1v+=m; q1=fmaf(m,m,q1); mn1=fminf(mn1,m); mx1=fmaxf(mx1,m);
    }
  }
  float dg = (float)(r1-r0);
  float dc = fmaxf(dg, 1.f);
  bool has = dg > 0.f;
  u16* ah = ahi + (long long)wid*512;
  u16* al = alo + (long long)wid*512;
  auto put = [&](int idx, float val){
    u16 h = f2bf(val); ah[idx]=h; al[idx]=f2bf(val - bf2f(h));
  };
  {
    float mean = s0/dc;
    float var = q0/dc - mean*mean;
    float sd = sqrtf(fmaxf(var,0.f)+1e-5f);
    put(lane, mean); put(128+lane, sd);
    put(256+lane, has? mn0:0.f); put(384+lane, has? mx0:0.f);
  }
  {
    float mean = s1v/dc;
    float var = q1/dc - mean*mean;
    float sd = sqrtf(fmaxf(var,0.f)+1e-5f);
    put(64+lane, mean); put(192+lane, sd);
    put(320+lane, has? mn1:0.f); put(448+lane, has? mx1:0.f);
  }
}

// ---- fused PNA GEMM via split-bf16 MFMA (3-pass) ----
__global__ __launch_bounds__(256)
void k_mfma_fused(const u16* __restrict__ ahi, const u16* __restrict__ alo,
                  const u16* __restrict__ whi, const u16* __restrict__ wlo,
                  const int* __restrict__ rowptr, const int* __restrict__ inv,
                  const float* __restrict__ hp, const float* __restrict__ b_pna,
                  float* __restrict__ hout, int base, int M){
  __shared__ u16 As_hi[64][40];
  __shared__ u16 As_lo[64][40];
  __shared__ u16 Ws_hi[3][64][40];
  __shared__ u16 Ws_lo[3][64][40];
  int tid = threadIdx.x;
  int l = tid & 63;
  int wv = tid >> 6;
  int wm = wv >> 1, wn = wv & 1;
  int kg = l >> 4, lr = l & 15;
  int bm = blockIdx.x*64, bn = blockIdx.y*64;
  f32x4 acc[3][2][2] = {};
  int sr = tid >> 2;
  int seg = tid & 3;
  for(int k0=0; k0<512; k0+=32){
    {
      const short8 vh = *(const short8*)(ahi + (long long)(bm+sr)*512 + k0 + seg*8);
      const short8 vl = *(const short8*)(alo + (long long)(bm+sr)*512 + k0 + seg*8);
      *(short8*)&As_hi[sr][seg*8] = vh;
      *(short8*)&As_lo[sr][seg*8] = vl;
    }
    #pragma unroll
    for(int s=0;s<3;s++){
      const short8 vh = *(const short8*)(whi + (long long)(s*128+bn+sr)*512 + k0 + seg*8);
      const short8 vl = *(const short8*)(wlo + (long long)(s*128+bn+sr)*512 + k0 + seg*8);
      *(short8*)&Ws_hi[s][sr][seg*8] = vh;
      *(short8*)&Ws_lo[s][sr][seg*8] = vl;
    }
    __syncthreads();
    short8 ah[2], al[2];
    #pragma unroll
    for(int mi=0;mi<2;mi++){
      ah[mi] = *(const short8*)&As_hi[wm*32+mi*16+lr][kg*8];
      al[mi] = *(const short8*)&As_lo[wm*32+mi*16+lr][kg*8];
    }
    #pragma unroll
    for(int s=0;s<3;s++){
      #pragma unroll
      for(int ni=0;ni<2;ni++){
        short8 bh = *(const short8*)&Ws_hi[s][wn*32+ni*16+lr][kg*8];
        short8 bl = *(const short8*)&Ws_lo[s][wn*32+ni*16+lr][kg*8];
        #pragma unroll
        for(int mi=0;mi<2;mi++){
          acc[s][mi][ni] = __builtin_amdgcn_mfma_f32_16x16x32_bf16(ah[mi], bh, acc[s][mi][ni], 0,0,0);
          acc[s][mi][ni] = __builtin_amdgcn_mfma_f32_16x16x32_bf16(al[mi], bh, acc[s][mi][ni], 0,0,0);
          acc[s][mi][ni] = __builtin_amdgcn_mfma_f32_16x16x32_bf16(ah[mi], bl, acc[s][mi][ni], 0,0,0);
        }
      }
    }
    __syncthreads();
  }
  #pragma unroll
  for(int mi=0;mi<2;mi++){
    #pragma unroll
    for(int reg=0;reg<4;reg++){
      int rl = bm + wm*32 + mi*16 + kg*4 + reg;
      if(rl >= M) continue;
      int v = base + rl;
      int d0 = rowptr[v], d1 = rowptr[v+1];
      float logd = log1pf((float)(d1-d0));
      float att = 1.0f/(logd + 1.0f);
      int iv = inv[v];
      #pragma unroll
      for(int ni=0;ni<2;ni++){
        int col = bn + wn*32 + ni*16 + lr;
        float o = acc[0][mi][ni][reg] + logd*acc[1][mi][ni][reg] + att*acc[2][mi][ni][reg] + b_pna[col];
        if(iv>=0) o += hp[(long long)iv*128 + col];
        hout[(long long)v*128 + col] = o;
      }
    }
  }
}

__global__ void k_center(const int* __restrict__ nodes, const int* __restrict__ q_sub,
                         int* __restrict__ cidx, int N, int Bq){
  int i = blockIdx.x*blockDim.x + threadIdx.x;
  if(i>=N) return;
  int b = nodes[2*i];
  if(b>=0 && b<Bq && nodes[2*i+1]==q_sub[b]) atomicMin((unsigned*)&cidx[b], (unsigned)i);
}

__global__ __launch_bounds__(64)
void k_cu(const float* __restrict__ hout, const int* __restrict__ cidx,
          const float* __restrict__ Wsc, float* __restrict__ cu, int Bq){
  int b = blockIdx.x, lane = threadIdx.x;
  int i = cidx[b]; if(i==0x7FFFFFFF) i=0;
  const float* hrow = hout + (long long)i*128;
  float p = fmaf(hrow[lane], Wsc[lane], hrow[64+lane]*Wsc[64+lane]);
  for(int o=32;o>0;o>>=1) p += __shfl_down(p, o);
  if(lane==0) cu[b]=p;
}

__global__ __launch_bounds__(256)
void k_alpha(float* __restrict__ hout, const int* __restrict__ nodes,
             const float* __restrict__ cu, const float* __restrict__ Wsc,
             const float* __restrict__ b_sc, const int* __restrict__ keep0,
             float* __restrict__ out_alpha, float* __restrict__ out_keep,
             float* __restrict__ ca, int N){
  int v = blockIdx.x*4 + (threadIdx.x>>6);
  int lane = threadIdx.x & 63;
  if(v>=N) return;
  float* hrow = hout + (long long)v*128;
  float h0 = hrow[lane], h1 = hrow[64+lane];
  float p = fmaf(h0, Wsc[128+lane], h1*Wsc[192+lane]);
  for(int o=32;o>0;o>>=1) p += __shfl_down(p,o);
  float t = __shfl(p, 0);
  int bnode = nodes[2*v];
  t += cu[bnode] + b_sc[0];
  float alpha = sigf(t);
  hrow[lane] = alpha*h0;
  hrow[64+lane] = alpha*h1;
  if(lane==0){
    out_alpha[v] = alpha;
    out_keep[v] = 0.f;
    int ent = nodes[2*v+1];
    ca[v] = keep0[v] ? -__builtin_inff() : (alpha + ((ent>=NUSER && ent<NUSER+NITEM)?BONUS:0.f));
  }
}

// ---- candidate compaction ----
__global__ void k_cand_count(const int* __restrict__ nodes, const int* __restrict__ keep0,
                             int* __restrict__ ccnt, int N, int Bq){
  __shared__ int h[64];
  int tid = threadIdx.x;
  if(tid < Bq) h[tid]=0;
  __syncthreads();
  int i = blockIdx.x*256 + tid;
  if(i<N && keep0[i]==0) atomicAdd(&h[nodes[2*i]], 1);
  __syncthreads();
  if(tid<Bq && h[tid]) atomicAdd(&ccnt[tid], h[tid]);
}

__global__ void k_cand_base(const int* __restrict__ ccnt, int* __restrict__ cbase,
                            int* __restrict__ ccur, int Bq){
  if(threadIdx.x==0 && blockIdx.x==0){
    int run=0;
    for(int b=0;b<Bq;b++){ cbase[b]=run; ccur[b]=run; run+=ccnt[b]; }
    cbase[Bq]=run;
  }
}

__global__ __launch_bounds__(256)
void k_cand_fill(const int* __restrict__ nodes, const int* __restrict__ keep0,
                 const float* __restrict__ ca, int* __restrict__ ccur,
                 unsigned long long* __restrict__ cand, int N, int Bq){
  __shared__ int h[64];
  __shared__ int basep[64];
  int tid = threadIdx.x;
  if(tid < Bq) h[tid]=0;
  __syncthreads();
  int i = blockIdx.x*256 + tid;
  bool valid = (i<N) && (keep0[i]==0);
  int b = 0, myofs = 0;
  if(valid){ b = nodes[2*i]; myofs = atomicAdd(&h[b], 1); }
  __syncthreads();
  if(tid < Bq && h[tid]) basep[tid] = atomicAdd(&ccur[tid], h[tid]);
  __syncthreads();
  if(valid){
    cand[basep[b] + myofs] = ((unsigned long long)fmap(ca[i])<<32) | (unsigned)(0x7FFFFFFF - i);
  }
}

// exact per-batch top-K: 8-level MSD radix select over distinct 64-bit keys
__global__ __launch_bounds__(256)
void k_topk3(const unsigned long long* __restrict__ cand, const int* __restrict__ cbase,
             const int* __restrict__ idl, const int* __restrict__ nl,
             float* __restrict__ out_keep){
  if(idl[0] >= nl[0]-1) return;
  int b = blockIdx.x, tid = threadIdx.x;
  int s = cbase[b];
  int n = cbase[b+1] - s;
  const unsigned long long* p = cand + s;
  if(n <= KTOP){
    for(int j=tid;j<n;j+=256)
      out_keep[0x7FFFFFFF - (int)(unsigned)(p[j] & 0xFFFFFFFFULL)] = 1.f;
    return;
  }
  __shared__ int hist[256];
  __shared__ int sc[256];
  __shared__ unsigned long long s_pfx;
  __shared__ int s_kneed;
  if(tid==0){ s_pfx=0ULL; s_kneed=KTOP; }
  __syncthreads();
  for(int shift=56; shift>=0; shift-=8){
    hist[tid]=0;
    __syncthreads();
    unsigned long long pfx = s_pfx;
    int kneed = s_kneed;
    int sh2 = shift + 8;
    for(int j=tid;j<n;j+=256){
      unsigned long long k = p[j];
      bool match = (sh2>=64) || ((k>>sh2) == (pfx>>sh2));
      if(match) atomicAdd(&hist[(int)((k>>shift)&255ULL)], 1);
    }
    __syncthreads();
    sc[tid] = hist[255-tid];
    __syncthreads();
    for(int off=1;off<256;off<<=1){
      int t = (tid>=off)? sc[tid-off] : 0;
      __syncthreads();
      sc[tid] += t;
      __syncthreads();
    }
    // GE(d) = sc[255-d]; GT(d) = (d==255)?0:sc[254-d]
    int d = tid;
    int gt = (d==255)? 0 : sc[254-d];
    int ge = sc[255-d];
    if(gt < kneed && kneed <= ge){
      s_pfx = pfx | (((unsigned long long)d)<<shift);
      s_kneed = kneed - gt;
    }
    __syncthreads();
  }
  unsigned long long T = s_pfx;   // exact Kth-largest key
  for(int j=tid;j<n;j+=256){
    if(p[j] >= T)
      out_keep[0x7FFFFFFF - (int)(unsigned)(p[j] & 0xFFFFFFFFULL)] = 1.f;
  }
}

__global__ void k_keepfin(const int* __restrict__ nodes, const int* __restrict__ keep0,
                          const int* __restrict__ idl, const int* __restrict__ nl,
                          float* __restrict__ out_keep, int N){
  int i = blockIdx.x*blockDim.x + threadIdx.x;
  if(i>=N) return;
  if(idl[0] < nl[0]-1){
    if(keep0[i]) out_keep[i]=1.f;
  } else {
    int ent = nodes[2*i+1];
    out_keep[i] = (ent>=NUSER && ent<NUSER+NITEM) ? 1.f : 0.f;
  }
}

extern "C" void kernel_launch(void* const* d_in, const int* in_sizes, int n_in,
                              void* d_out, int out_size, void* d_ws, size_t ws_size,
                              hipStream_t stream){
  const int*   q_sub    = (const int*)d_in[0];
  const float* hidden   = (const float*)d_in[2];
  const int*   edges    = (const int*)d_in[3];
  const int*   nodes    = (const int*)d_in[4];
  const int*   idl      = (const int*)d_in[5];
  const int*   nl       = (const int*)d_in[6];
  const int*   oni      = (const int*)d_in[7];
  const float* rel_tab  = (const float*)d_in[8];
  const float* W_i      = (const float*)d_in[9];
  const float* W_h      = (const float*)d_in[10];
  const float* b_i      = (const float*)d_in[11];
  const float* b_h      = (const float*)d_in[12];
  const float* W_pna    = (const float*)d_in[13];
  const float* b_pna    = (const float*)d_in[14];
  const float* W_sc     = (const float*)d_in[15];
  const float* b_sc     = (const float*)d_in[16];

  int Bq = in_sizes[0];
  int NP = in_sizes[2]/128;
  int E  = in_sizes[3]/6;
  int N  = in_sizes[4]/2;
  int NR = in_sizes[8]/128;
  long long nd = (long long)N*128;
  int nb = (N+255)/256;

  size_t off = 0;
  auto alloc = [&](size_t bytes)->void*{
    void* r = (char*)d_ws + off;
    off += (bytes + 255) & ~(size_t)255;
    return r;
  };
  // ---- fixed region ----
  float* gh_t    = (float*)alloc((size_t)NP*384*4);        // 30.7 MB
  float* gi_t    = (float*)alloc((size_t)NR*384*4);
  u16*   wbig_hi = (u16*)  alloc((size_t)384*512*2);
  u16*   wbig_lo = (u16*)  alloc((size_t)384*512*2);
  u16*   whT_hi  = (u16*)  alloc((size_t)384*128*2);
  u16*   whT_lo  = (u16*)  alloc((size_t)384*128*2);
  u16*   w4T_hi  = (u16*)  alloc((size_t)128*128*2);
  u16*   w4T_lo  = (u16*)  alloc((size_t)128*128*2);
  float* hp      = (float*)alloc((size_t)NP*128*4);        // 10.2 MB
  int*   rowptr  = (int*)  alloc((size_t)(N+1)*4);
  int*   cursor  = (int*)  alloc((size_t)N*4);
  int*   deg_i   = (int*)  alloc((size_t)N*4);
  int*   bsum    = (int*)  alloc((size_t)((nb+63)&~63)*4);
  int*   eid     = (int*)  alloc((size_t)E*4);
  int*   inv     = (int*)  alloc((size_t)N*4);
  int*   kp0     = (int*)  alloc((size_t)N*4);
  int*   cidx    = (int*)  alloc((size_t)Bq*4);
  float* cu      = (float*)alloc((size_t)Bq*4);
  float* ca      = (float*)alloc((size_t)N*4);
  unsigned long long* cand = (unsigned long long*)alloc((size_t)N*8);
  int*   ccnt    = (int*)  alloc((size_t)Bq*4);
  int*   cbase   = (int*)  alloc((size_t)(Bq+1)*4);
  int*   ccur    = (int*)  alloc((size_t)Bq*4);
  // ---- overlay region: hhi/hlo live only until mfma_ab calls; agg planes reuse it ----
  size_t off_ov = off;
  size_t avail = (ws_size > off_ov) ? (ws_size - off_ov) : 0;
  u16* hhi = (u16*)((char*)d_ws + off_ov);
  u16* hlo = hhi + (size_t)(NP+64)*128;
  // agg planes: bytes/row across both planes = 512*2*2 = 2048
  long long rows_cap = (long long)(avail/2048) - 64;
  int Nr64 = (N+63)&~63;
  int CH = (int)((rows_cap < 1024) ? 1024 : rows_cap);
  CH &= ~63;
  if(CH > Nr64) CH = Nr64;
  u16* ahi = (u16*)((char*)d_ws + off_ov);
  u16* alo = ahi + (size_t)(CH+64)*512;

  float* out_h = (float*)d_out;
  float* out_alpha = out_h + nd;
  float* out_keep = out_alpha + N;

  k_init<<<(N+255)/256,256,0,stream>>>(deg_i, inv, kp0, cidx, ccnt, N, Bq);
  k_small_gemm<<<(NR*384+255)/256,256,0,stream>>>(rel_tab, W_i, b_i, gi_t, NR, 384, 128);
  k_prep<<<(262144+255)/256,256,0,stream>>>(W_pna, W_h, wbig_hi, wbig_lo, whT_hi, whT_lo, w4T_hi, w4T_lo);
  k_split_h<<<((size_t)NP*128+255)/256,256,0,stream>>>(hidden, hhi, hlo, NP*128);
  k_mfma_ab<<<dim3((NP+63)/64, 384/64),256,0,stream>>>(hhi, hlo, whT_hi, whT_lo, b_h, gh_t, NP, 384, 128);
  k_mfma_ab<<<dim3((NP+63)/64, 128/64),256,0,stream>>>(hhi, hlo, w4T_hi, w4T_lo, nullptr, hp, NP, 128, 128);
  k_scatter_old<<<(NP+255)/256,256,0,stream>>>(oni, inv, kp0, NP, N);
  k_count<<<(E+255)/256,256,0,stream>>>(edges, deg_i, E);
  k_scan1<<<nb,256,0,stream>>>(deg_i, rowptr, bsum, N);
  k_scan2<<<1,512,0,stream>>>(bsum, nb);
  k_scan3<<<(N+255)/256,256,0,stream>>>(rowptr, bsum, cursor, N, E);
  k_fill<<<(E+255)/256,256,0,stream>>>(edges, cursor, eid, E);
  for(int base=0; base<N; base+=CH){
    int M = (N-base < CH) ? (N-base) : CH;
    k_aggcsr<<<((size_t)M*64+255)/256,256,0,stream>>>(edges, eid, rowptr, gi_t, gh_t, hidden, ahi, alo, base, M);
    k_mfma_fused<<<dim3((M+63)/64, 2),256,0,stream>>>(ahi, alo, wbig_hi, wbig_lo, rowptr, inv, hp, b_pna, out_h, base, M);
  }
  k_center<<<(N+255)/256,256,0,stream>>>(nodes, q_sub, cidx, N, Bq);
  k_cu<<<Bq,64,0,stream>>>(out_h, cidx, W_sc, cu, Bq);
  k_alpha<<<(N+3)/4,256,0,stream>>>(out_h, nodes, cu, W_sc, b_sc, kp0, out_alpha, out_keep, ca, N);
  k_cand_count<<<(N+255)/256,256,0,stream>>>(nodes, kp0, ccnt, N, Bq);
  k_cand_base<<<1,64,0,stream>>>(ccnt, cbase, ccur, Bq);
  k_cand_fill<<<(N+255)/256,256,0,stream>>>(nodes, kp0, ca, ccur, cand, N, Bq);
  k_topk3<<<Bq,256,0,stream>>>(cand, cbase, idl, nl, out_keep);
  k_keepfin<<<(N+255)/256,256,0,stream>>>(nodes, kp0, idl, nl, out_keep, N);
}

// Round 8
// 632.452 us; speedup vs baseline: 7.3585x; 1.0282x over previous
//
#include <hip/hip_runtime.h>
#include <hip/hip_bf16.h>
#include <cstdint>

#define NUSER 50000
#define NITEM 30000
#define KTOP 50
#define BONUS 0.05f

typedef __attribute__((ext_vector_type(8))) short short8;
typedef __attribute__((ext_vector_type(4))) float f32x4;
typedef unsigned short u16;

__device__ __forceinline__ float sigf(float x){ return 1.0f/(1.0f + __expf(-x)); }
__device__ __forceinline__ unsigned fmap(float x){ unsigned b=__float_as_uint(x); return (b&0x80000000u)? ~b : (b|0x80000000u); }
// round-to-nearest-even f32 -> bf16 bits
__device__ __forceinline__ u16 f2bf(float x){ unsigned u=__float_as_uint(x); unsigned r=(u + 0x7FFFu + ((u>>16)&1u))>>16; return (u16)r; }
__device__ __forceinline__ float bf2f(u16 b){ return __uint_as_float(((unsigned)b)<<16); }

__global__ void k_init(int* deg_i, int* inv, int* keep0, int* cidx, int* ccnt, int N, int Bq){
  int i = blockIdx.x*blockDim.x + threadIdx.x;
  if(i < N){ deg_i[i]=0; inv[i]=-1; keep0[i]=0; }
  if(i < Bq){ cidx[i]=0x7FFFFFFF; ccnt[i]=0; }
}

// tiny GEMM (thread per output) for gi_table (27x384)
__global__ void k_small_gemm(const float* __restrict__ A, const float* __restrict__ W,
                             const float* __restrict__ bias, float* __restrict__ C,
                             int M, int Nn, int Kk){
  int i = blockIdx.x*blockDim.x + threadIdx.x;
  if(i >= M*Nn) return;
  int r = i/Nn, c = i - r*Nn;
  float acc = bias ? bias[c] : 0.f;
  for(int k=0;k<Kk;k++) acc = fmaf(A[r*Kk+k], W[k*Nn+c], acc);
  C[i] = acc;
}

// weight prep: split-bf16 transposed tables
__global__ void k_prep(const float* __restrict__ Wp, const float* __restrict__ Wh,
                       u16* __restrict__ wbig_hi, u16* __restrict__ wbig_lo,
                       u16* __restrict__ whT_hi, u16* __restrict__ whT_lo,
                       u16* __restrict__ w4T_hi, u16* __restrict__ w4T_lo){
  int i = blockIdx.x*blockDim.x + threadIdx.x;
  if(i >= 262144) return;
  float v; u16* ph; u16* pl; int j;
  if(i < 196608){
    int c = i>>9, k = i&511;
    v = Wp[((c>>7)*512 + k)*128 + (c&127)];
    ph = wbig_hi; pl = wbig_lo; j = i;
  } else if(i < 245760){
    j = i - 196608;
    int c = j>>7, k = j&127;
    v = Wh[k*384 + c];
    ph = whT_hi; pl = whT_lo;
  } else {
    j = i - 245760;
    int c = j>>7, k = j&127;
    v = Wp[(1536 + k)*128 + c];
    ph = w4T_hi; pl = w4T_lo;
  }
  u16 h = f2bf(v);
  ph[j] = h;
  pl[j] = f2bf(v - bf2f(h));
}

// split hidden [NP x 128] into hi/lo bf16
__global__ void k_split_h(const float* __restrict__ hidden, u16* __restrict__ hhi,
                          u16* __restrict__ hlo, int n){
  int i = blockIdx.x*blockDim.x + threadIdx.x;
  if(i>=n) return;
  float v = hidden[i];
  u16 h = f2bf(v);
  hhi[i]=h; hlo[i]=f2bf(v - bf2f(h));
}

// generic split-bf16 MFMA GEMM (3-pass): C[M x Nn] = A[M x K] @ WT[Nn x K]^T (+bias)
__global__ __launch_bounds__(256)
void k_mfma_ab(const u16* __restrict__ Ahi, const u16* __restrict__ Alo,
               const u16* __restrict__ WThi, const u16* __restrict__ WTlo,
               const float* __restrict__ bias, float* __restrict__ C,
               int M, int Nn, int K){
  __shared__ u16 As_hi[64][40];
  __shared__ u16 As_lo[64][40];
  __shared__ u16 Ws_hi[64][40];
  __shared__ u16 Ws_lo[64][40];
  int tid = threadIdx.x;
  int l = tid & 63, wv = tid >> 6;
  int wm = wv >> 1, wn = wv & 1;
  int kg = l >> 4, lr = l & 15;
  int bm = blockIdx.x*64, bn = blockIdx.y*64;
  f32x4 acc[2][2] = {};
  int sr = tid >> 2, seg = tid & 3;
  for(int k0=0; k0<K; k0+=32){
    *(short8*)&As_hi[sr][seg*8] = *(const short8*)(Ahi + (long long)(bm+sr)*K + k0 + seg*8);
    *(short8*)&As_lo[sr][seg*8] = *(const short8*)(Alo + (long long)(bm+sr)*K + k0 + seg*8);
    *(short8*)&Ws_hi[sr][seg*8] = *(const short8*)(WThi + (long long)(bn+sr)*K + k0 + seg*8);
    *(short8*)&Ws_lo[sr][seg*8] = *(const short8*)(WTlo + (long long)(bn+sr)*K + k0 + seg*8);
    __syncthreads();
    short8 ah[2], al[2], bh[2], bl[2];
    #pragma unroll
    for(int mi=0;mi<2;mi++){
      ah[mi] = *(const short8*)&As_hi[wm*32+mi*16+lr][kg*8];
      al[mi] = *(const short8*)&As_lo[wm*32+mi*16+lr][kg*8];
    }
    #pragma unroll
    for(int ni=0;ni<2;ni++){
      bh[ni] = *(const short8*)&Ws_hi[wn*32+ni*16+lr][kg*8];
      bl[ni] = *(const short8*)&Ws_lo[wn*32+ni*16+lr][kg*8];
    }
    #pragma unroll
    for(int ni=0;ni<2;ni++)
      #pragma unroll
      for(int mi=0;mi<2;mi++){
        acc[mi][ni] = __builtin_amdgcn_mfma_f32_16x16x32_bf16(ah[mi], bh[ni], acc[mi][ni], 0,0,0);
        acc[mi][ni] = __builtin_amdgcn_mfma_f32_16x16x32_bf16(al[mi], bh[ni], acc[mi][ni], 0,0,0);
        acc[mi][ni] = __builtin_amdgcn_mfma_f32_16x16x32_bf16(ah[mi], bl[ni], acc[mi][ni], 0,0,0);
      }
    __syncthreads();
  }
  #pragma unroll
  for(int mi=0;mi<2;mi++)
    #pragma unroll
    for(int reg=0;reg<4;reg++){
      int row = bm + wm*32 + mi*16 + kg*4 + reg;
      if(row >= M) continue;
      #pragma unroll
      for(int ni=0;ni<2;ni++){
        int col = bn + wn*32 + ni*16 + lr;
        float o = acc[mi][ni][reg];
        if(bias) o += bias[col];
        C[(long long)row*Nn + col] = o;
      }
    }
}

__global__ void k_scatter_old(const int* __restrict__ oni, int* __restrict__ inv,
                              int* __restrict__ keep0, int NP, int N){
  int i = blockIdx.x*blockDim.x + threadIdx.x;
  if(i>=NP) return;
  int v = oni[i];
  if(v>=0 && v<N){ inv[v]=i; keep0[v]=1; }
}

// ---- CSR build ----
__global__ void k_count(const int* __restrict__ edges, int* __restrict__ deg_i, int E){
  int e = blockIdx.x*blockDim.x + threadIdx.x;
  if(e<E) atomicAdd(&deg_i[edges[(long long)e*6+5]], 1);
}

__global__ __launch_bounds__(256)
void k_scan1(const int* __restrict__ deg_i, int* __restrict__ rowptr, int* __restrict__ bsum, int N){
  __shared__ int sc[256];
  int tid=threadIdx.x; int i = blockIdx.x*256+tid;
  int v = (i<N)? deg_i[i] : 0;
  sc[tid]=v; __syncthreads();
  for(int off=1; off<256; off<<=1){
    int t = (tid>=off)? sc[tid-off] : 0;
    __syncthreads();
    sc[tid] += t;
    __syncthreads();
  }
  if(i<N) rowptr[i] = sc[tid] - v;
  if(tid==255) bsum[blockIdx.x] = sc[255];
}

// parallel exclusive scan of block sums (nb <= 512)
__global__ __launch_bounds__(512)
void k_scan2(int* __restrict__ bsum, int nb){
  __shared__ int sc[512];
  int tid = threadIdx.x;
  int v = (tid<nb)? bsum[tid] : 0;
  sc[tid]=v; __syncthreads();
  for(int off=1; off<512; off<<=1){
    int t = (tid>=off)? sc[tid-off] : 0;
    __syncthreads();
    sc[tid] += t;
    __syncthreads();
  }
  if(tid<nb) bsum[tid] = sc[tid] - v;
}

__global__ void k_scan3(int* __restrict__ rowptr, const int* __restrict__ bsum,
                        int* __restrict__ cursor, int N, int E){
  int i = blockIdx.x*blockDim.x + threadIdx.x;
  if(i<N){ int r = rowptr[i] + bsum[i>>8]; rowptr[i]=r; cursor[i]=r; }
  if(i==0) rowptr[N]=E;
}

__global__ void k_fill(const int* __restrict__ edges, int* __restrict__ cursor,
                       int* __restrict__ eid, int E){
  int e = blockIdx.x*blockDim.x + threadIdx.x;
  if(e<E){ int obj = edges[(long long)e*6+5]; int p = atomicAdd(&cursor[obj],1); eid[p]=e; }
}

// ---- per-node aggregation (one wave per node), writes split-bf16 agg planes ----
__global__ __launch_bounds__(256)
void k_aggcsr(const int* __restrict__ edges, const int* __restrict__ eid,
              const int* __restrict__ rowptr, const float* __restrict__ gi_t,
              const float* __restrict__ gh_t, const float* __restrict__ hidden,
              u16* __restrict__ ahi, u16* __restrict__ alo, int base, int M){
  int wid = (blockIdx.x*256 + threadIdx.x)>>6;
  int lane = threadIdx.x & 63;
  if(wid >= M) return;
  int v = base + wid;
  int r0 = rowptr[v], r1 = rowptr[v+1];
  float s0=0.f, q0=0.f, s1v=0.f, q1=0.f;
  float mn0=INFINITY, mx0=-INFINITY, mn1=INFINITY, mx1=-INFINITY;
  for(int j=r0;j<r1;++j){
    int e = eid[j];
    const int* er = edges + (long long)e*6;
    int sub = er[4], rel = er[2];
    const float* gi = gi_t + (long long)rel*384;
    const float* gh = gh_t + (long long)sub*384;
    const float* hs = hidden + (long long)sub*128;
    {
      int d = lane;
      float r = sigf(gi[d]+gh[d]);
      float z = sigf(gi[128+d]+gh[128+d]);
      float n = tanhf(gi[256+d] + r*gh[256+d]);
      float m = (1.f-z)*n + z*hs[d];
      s0+=m; q0=fmaf(m,m,q0); mn0=fminf(mn0,m); mx0=fmaxf(mx0,m);
    }
    {
      int d = lane+64;
      float r = sigf(gi[d]+gh[d]);
      float z = sigf(gi[128+d]+gh[128+d]);
      float n = tanhf(gi[256+d] + r*gh[256+d]);
      float m = (1.f-z)*n + z*hs[d];
      s1v+=m; q1=fmaf(m,m,q1); mn1=fminf(mn1,m); mx1=fmaxf(mx1,m);
    }
  }
  float dg = (float)(r1-r0);
  float dc = fmaxf(dg, 1.f);
  bool has = dg > 0.f;
  u16* ah = ahi + (long long)wid*512;
  u16* al = alo + (long long)wid*512;
  auto put = [&](int idx, float val){
    u16 h = f2bf(val); ah[idx]=h; al[idx]=f2bf(val - bf2f(h));
  };
  {
    float mean = s0/dc;
    float var = q0/dc - mean*mean;
    float sd = sqrtf(fmaxf(var,0.f)+1e-5f);
    put(lane, mean); put(128+lane, sd);
    put(256+lane, has? mn0:0.f); put(384+lane, has? mx0:0.f);
  }
  {
    float mean = s1v/dc;
    float var = q1/dc - mean*mean;
    float sd = sqrtf(fmaxf(var,0.f)+1e-5f);
    put(64+lane, mean); put(192+lane, sd);
    put(320+lane, has? mn1:0.f); put(448+lane, has? mx1:0.f);
  }
}

// ---- fused PNA GEMM via split-bf16 MFMA (3-pass), 128-row tile ----
// block: 256 thr = 4 waves (2m x 2n); tile M=128 x (3 slices x 64 cols); per wave 4mi x 2ni frags.
__global__ __launch_bounds__(256, 2)
void k_mfma_fused(const u16* __restrict__ ahi, const u16* __restrict__ alo,
                  const u16* __restrict__ whi, const u16* __restrict__ wlo,
                  const int* __restrict__ rowptr, const int* __restrict__ inv,
                  const float* __restrict__ hp, const float* __restrict__ b_pna,
                  float* __restrict__ hout, int base, int M){
  __shared__ u16 As_hi[128][40];
  __shared__ u16 As_lo[128][40];
  __shared__ u16 Ws_hi[3][64][40];
  __shared__ u16 Ws_lo[3][64][40];
  int tid = threadIdx.x;
  int l = tid & 63;
  int wv = tid >> 6;
  int wm = wv >> 1, wn = wv & 1;
  int kg = l >> 4, lr = l & 15;
  int bm = blockIdx.x*128, bn = blockIdx.y*64;
  f32x4 acc[3][4][2] = {};
  int ar = tid >> 1;            // 0..127 (A row)
  int as_ = (tid & 1)*2;        // seg base {0,2}
  for(int k0=0; k0<512; k0+=32){
    // stage A: 128 rows, 2 segs/thread/plane
    {
      const u16* gh_ = ahi + (long long)(bm+ar)*512 + k0 + as_*8;
      const u16* gl_ = alo + (long long)(bm+ar)*512 + k0 + as_*8;
      *(short8*)&As_hi[ar][as_*8]     = *(const short8*)(gh_);
      *(short8*)&As_hi[ar][as_*8+8]   = *(const short8*)(gh_+8);
      *(short8*)&As_lo[ar][as_*8]     = *(const short8*)(gl_);
      *(short8*)&As_lo[ar][as_*8+8]   = *(const short8*)(gl_+8);
    }
    // stage W: 3 slices x 64 rows x 4 segs x 2 planes = 1536 16B-stores / 256 thr = 6 each
    #pragma unroll
    for(int t=0;t<6;t++){
      int li = tid + t*256;
      int seg = li & 3;
      int rp  = li >> 2;            // 0..383
      int row = (rp >= 192) ? rp-192 : rp;
      int s = row >> 6, r6 = row & 63;
      const u16* src = ((rp >= 192) ? wlo : whi) + (long long)(s*128 + bn + r6)*512 + k0 + seg*8;
      u16* dst = (rp >= 192) ? &Ws_lo[s][r6][seg*8] : &Ws_hi[s][r6][seg*8];
      *(short8*)dst = *(const short8*)src;
    }
    __syncthreads();
    short8 ah[4], al[4];
    #pragma unroll
    for(int mi=0;mi<4;mi++){
      ah[mi] = *(const short8*)&As_hi[wm*64+mi*16+lr][kg*8];
      al[mi] = *(const short8*)&As_lo[wm*64+mi*16+lr][kg*8];
    }
    #pragma unroll
    for(int s=0;s<3;s++){
      #pragma unroll
      for(int ni=0;ni<2;ni++){
        short8 bh = *(const short8*)&Ws_hi[s][wn*32+ni*16+lr][kg*8];
        short8 bl = *(const short8*)&Ws_lo[s][wn*32+ni*16+lr][kg*8];
        #pragma unroll
        for(int mi=0;mi<4;mi++){
          acc[s][mi][ni] = __builtin_amdgcn_mfma_f32_16x16x32_bf16(ah[mi], bh, acc[s][mi][ni], 0,0,0);
          acc[s][mi][ni] = __builtin_amdgcn_mfma_f32_16x16x32_bf16(al[mi], bh, acc[s][mi][ni], 0,0,0);
          acc[s][mi][ni] = __builtin_amdgcn_mfma_f32_16x16x32_bf16(ah[mi], bl, acc[s][mi][ni], 0,0,0);
        }
      }
    }
    __syncthreads();
  }
  #pragma unroll
  for(int mi=0;mi<4;mi++){
    #pragma unroll
    for(int reg=0;reg<4;reg++){
      int rl = bm + wm*64 + mi*16 + kg*4 + reg;
      if(rl >= M) continue;
      int v = base + rl;
      int d0 = rowptr[v], d1 = rowptr[v+1];
      float logd = log1pf((float)(d1-d0));
      float att = 1.0f/(logd + 1.0f);
      int iv = inv[v];
      #pragma unroll
      for(int ni=0;ni<2;ni++){
        int col = bn + wn*32 + ni*16 + lr;
        float o = acc[0][mi][ni][reg] + logd*acc[1][mi][ni][reg] + att*acc[2][mi][ni][reg] + b_pna[col];
        if(iv>=0) o += hp[(long long)iv*128 + col];
        hout[(long long)v*128 + col] = o;
      }
    }
  }
}

__global__ void k_center(const int* __restrict__ nodes, const int* __restrict__ q_sub,
                         int* __restrict__ cidx, int N, int Bq){
  int i = blockIdx.x*blockDim.x + threadIdx.x;
  if(i>=N) return;
  int b = nodes[2*i];
  if(b>=0 && b<Bq && nodes[2*i+1]==q_sub[b]) atomicMin((unsigned*)&cidx[b], (unsigned)i);
}

__global__ __launch_bounds__(64)
void k_cu(const float* __restrict__ hout, const int* __restrict__ cidx,
          const float* __restrict__ Wsc, float* __restrict__ cu, int Bq){
  int b = blockIdx.x, lane = threadIdx.x;
  int i = cidx[b]; if(i==0x7FFFFFFF) i=0;
  const float* hrow = hout + (long long)i*128;
  float p = fmaf(hrow[lane], Wsc[lane], hrow[64+lane]*Wsc[64+lane]);
  for(int o=32;o>0;o>>=1) p += __shfl_down(p, o);
  if(lane==0) cu[b]=p;
}

__global__ __launch_bounds__(256)
void k_alpha(float* __restrict__ hout, const int* __restrict__ nodes,
             const float* __restrict__ cu, const float* __restrict__ Wsc,
             const float* __restrict__ b_sc, const int* __restrict__ keep0,
             float* __restrict__ out_alpha, float* __restrict__ out_keep,
             float* __restrict__ ca, int N){
  int v = blockIdx.x*4 + (threadIdx.x>>6);
  int lane = threadIdx.x & 63;
  if(v>=N) return;
  float* hrow = hout + (long long)v*128;
  float h0 = hrow[lane], h1 = hrow[64+lane];
  float p = fmaf(h0, Wsc[128+lane], h1*Wsc[192+lane]);
  for(int o=32;o>0;o>>=1) p += __shfl_down(p,o);
  float t = __shfl(p, 0);
  int bnode = nodes[2*v];
  t += cu[bnode] + b_sc[0];
  float alpha = sigf(t);
  hrow[lane] = alpha*h0;
  hrow[64+lane] = alpha*h1;
  if(lane==0){
    out_alpha[v] = alpha;
    out_keep[v] = 0.f;
    int ent = nodes[2*v+1];
    ca[v] = keep0[v] ? -__builtin_inff() : (alpha + ((ent>=NUSER && ent<NUSER+NITEM)?BONUS:0.f));
  }
}

// ---- candidate compaction ----
__global__ void k_cand_count(const int* __restrict__ nodes, const int* __restrict__ keep0,
                             int* __restrict__ ccnt, int N, int Bq){
  __shared__ int h[64];
  int tid = threadIdx.x;
  if(tid < Bq) h[tid]=0;
  __syncthreads();
  int i = blockIdx.x*256 + tid;
  if(i<N && keep0[i]==0) atomicAdd(&h[nodes[2*i]], 1);
  __syncthreads();
  if(tid<Bq && h[tid]) atomicAdd(&ccnt[tid], h[tid]);
}

__global__ void k_cand_base(const int* __restrict__ ccnt, int* __restrict__ cbase,
                            int* __restrict__ ccur, int Bq){
  if(threadIdx.x==0 && blockIdx.x==0){
    int run=0;
    for(int b=0;b<Bq;b++){ cbase[b]=run; ccur[b]=run; run+=ccnt[b]; }
    cbase[Bq]=run;
  }
}

__global__ __launch_bounds__(256)
void k_cand_fill(const int* __restrict__ nodes, const int* __restrict__ keep0,
                 const float* __restrict__ ca, int* __restrict__ ccur,
                 unsigned long long* __restrict__ cand, int N, int Bq){
  __shared__ int h[64];
  __shared__ int basep[64];
  int tid = threadIdx.x;
  if(tid < Bq) h[tid]=0;
  __syncthreads();
  int i = blockIdx.x*256 + tid;
  bool valid = (i<N) && (keep0[i]==0);
  int b = 0, myofs = 0;
  if(valid){ b = nodes[2*i]; myofs = atomicAdd(&h[b], 1); }
  __syncthreads();
  if(tid < Bq && h[tid]) basep[tid] = atomicAdd(&ccur[tid], h[tid]);
  __syncthreads();
  if(valid){
    cand[basep[b] + myofs] = ((unsigned long long)fmap(ca[i])<<32) | (unsigned)(0x7FFFFFFF - i);
  }
}

// exact per-batch top-K: 8-level MSD radix select over distinct 64-bit keys
__global__ __launch_bounds__(256)
void k_topk3(const unsigned long long* __restrict__ cand, const int* __restrict__ cbase,
             const int* __restrict__ idl, const int* __restrict__ nl,
             float* __restrict__ out_keep){
  if(idl[0] >= nl[0]-1) return;
  int b = blockIdx.x, tid = threadIdx.x;
  int s = cbase[b];
  int n = cbase[b+1] - s;
  const unsigned long long* p = cand + s;
  if(n <= KTOP){
    for(int j=tid;j<n;j+=256)
      out_keep[0x7FFFFFFF - (int)(unsigned)(p[j] & 0xFFFFFFFFULL)] = 1.f;
    return;
  }
  __shared__ int hist[256];
  __shared__ int sc[256];
  __shared__ unsigned long long s_pfx;
  __shared__ int s_kneed;
  if(tid==0){ s_pfx=0ULL; s_kneed=KTOP; }
  __syncthreads();
  for(int shift=56; shift>=0; shift-=8){
    hist[tid]=0;
    __syncthreads();
    unsigned long long pfx = s_pfx;
    int kneed = s_kneed;
    int sh2 = shift + 8;
    for(int j=tid;j<n;j+=256){
      unsigned long long k = p[j];
      bool match = (sh2>=64) || ((k>>sh2) == (pfx>>sh2));
      if(match) atomicAdd(&hist[(int)((k>>shift)&255ULL)], 1);
    }
    __syncthreads();
    sc[tid] = hist[255-tid];
    __syncthreads();
    for(int off=1;off<256;off<<=1){
      int t = (tid>=off)? sc[tid-off] : 0;
      __syncthreads();
      sc[tid] += t;
      __syncthreads();
    }
    int d = tid;
    int gt = (d==255)? 0 : sc[254-d];
    int ge = sc[255-d];
    if(gt < kneed && kneed <= ge){
      s_pfx = pfx | (((unsigned long long)d)<<shift);
      s_kneed = kneed - gt;
    }
    __syncthreads();
  }
  unsigned long long T = s_pfx;
  for(int j=tid;j<n;j+=256){
    if(p[j] >= T)
      out_keep[0x7FFFFFFF - (int)(unsigned)(p[j] & 0xFFFFFFFFULL)] = 1.f;
  }
}

__global__ void k_keepfin(const int* __restrict__ nodes, const int* __restrict__ keep0,
                          const int* __restrict__ idl, const int* __restrict__ nl,
                          float* __restrict__ out_keep, int N){
  int i = blockIdx.x*blockDim.x + threadIdx.x;
  if(i>=N) return;
  if(idl[0] < nl[0]-1){
    if(keep0[i]) out_keep[i]=1.f;
  } else {
    int ent = nodes[2*i+1];
    out_keep[i] = (ent>=NUSER && ent<NUSER+NITEM) ? 1.f : 0.f;
  }
}

extern "C" void kernel_launch(void* const* d_in, const int* in_sizes, int n_in,
                              void* d_out, int out_size, void* d_ws, size_t ws_size,
                              hipStream_t stream){
  const int*   q_sub    = (const int*)d_in[0];
  const float* hidden   = (const float*)d_in[2];
  const int*   edges    = (const int*)d_in[3];
  const int*   nodes    = (const int*)d_in[4];
  const int*   idl      = (const int*)d_in[5];
  const int*   nl       = (const int*)d_in[6];
  const int*   oni      = (const int*)d_in[7];
  const float* rel_tab  = (const float*)d_in[8];
  const float* W_i      = (const float*)d_in[9];
  const float* W_h      = (const float*)d_in[10];
  const float* b_i      = (const float*)d_in[11];
  const float* b_h      = (const float*)d_in[12];
  const float* W_pna    = (const float*)d_in[13];
  const float* b_pna    = (const float*)d_in[14];
  const float* W_sc     = (const float*)d_in[15];
  const float* b_sc     = (const float*)d_in[16];

  int Bq = in_sizes[0];
  int NP = in_sizes[2]/128;
  int E  = in_sizes[3]/6;
  int N  = in_sizes[4]/2;
  int NR = in_sizes[8]/128;
  long long nd = (long long)N*128;
  int nb = (N+255)/256;

  size_t off = 0;
  auto alloc = [&](size_t bytes)->void*{
    void* r = (char*)d_ws + off;
    off += (bytes + 255) & ~(size_t)255;
    return r;
  };
  // ---- fixed region ----
  float* gh_t    = (float*)alloc((size_t)NP*384*4);
  float* gi_t    = (float*)alloc((size_t)NR*384*4);
  u16*   wbig_hi = (u16*)  alloc((size_t)384*512*2);
  u16*   wbig_lo = (u16*)  alloc((size_t)384*512*2);
  u16*   whT_hi  = (u16*)  alloc((size_t)384*128*2);
  u16*   whT_lo  = (u16*)  alloc((size_t)384*128*2);
  u16*   w4T_hi  = (u16*)  alloc((size_t)128*128*2);
  u16*   w4T_lo  = (u16*)  alloc((size_t)128*128*2);
  float* hp      = (float*)alloc((size_t)NP*128*4);
  int*   rowptr  = (int*)  alloc((size_t)(N+1)*4);
  int*   cursor  = (int*)  alloc((size_t)N*4);
  int*   deg_i   = (int*)  alloc((size_t)N*4);
  int*   bsum    = (int*)  alloc((size_t)((nb+63)&~63)*4);
  int*   eid     = (int*)  alloc((size_t)E*4);
  int*   inv     = (int*)  alloc((size_t)N*4);
  int*   kp0     = (int*)  alloc((size_t)N*4);
  int*   cidx    = (int*)  alloc((size_t)Bq*4);
  float* cu      = (float*)alloc((size_t)Bq*4);
  float* ca      = (float*)alloc((size_t)N*4);
  unsigned long long* cand = (unsigned long long*)alloc((size_t)N*8);
  int*   ccnt    = (int*)  alloc((size_t)Bq*4);
  int*   cbase   = (int*)  alloc((size_t)(Bq+1)*4);
  int*   ccur    = (int*)  alloc((size_t)Bq*4);
  // ---- overlay region: hhi/hlo live only until mfma_ab calls; agg planes reuse it ----
  size_t off_ov = off;
  size_t avail = (ws_size > off_ov) ? (ws_size - off_ov) : 0;
  u16* hhi = (u16*)((char*)d_ws + off_ov);
  u16* hlo = hhi + (size_t)(NP+64)*128;
  long long rows_cap = (long long)(avail/2048) - 128;
  int Nr128 = (N+127)&~127;
  int CH = (int)((rows_cap < 1024) ? 1024 : rows_cap);
  CH &= ~127;
  if(CH > Nr128) CH = Nr128;
  u16* ahi = (u16*)((char*)d_ws + off_ov);
  u16* alo = ahi + (size_t)(CH+128)*512;

  float* out_h = (float*)d_out;
  float* out_alpha = out_h + nd;
  float* out_keep = out_alpha + N;

  k_init<<<(N+255)/256,256,0,stream>>>(deg_i, inv, kp0, cidx, ccnt, N, Bq);
  k_small_gemm<<<(NR*384+255)/256,256,0,stream>>>(rel_tab, W_i, b_i, gi_t, NR, 384, 128);
  k_prep<<<(262144+255)/256,256,0,stream>>>(W_pna, W_h, wbig_hi, wbig_lo, whT_hi, whT_lo, w4T_hi, w4T_lo);
  k_split_h<<<((size_t)NP*128+255)/256,256,0,stream>>>(hidden, hhi, hlo, NP*128);
  k_mfma_ab<<<dim3((NP+63)/64, 384/64),256,0,stream>>>(hhi, hlo, whT_hi, whT_lo, b_h, gh_t, NP, 384, 128);
  k_mfma_ab<<<dim3((NP+63)/64, 128/64),256,0,stream>>>(hhi, hlo, w4T_hi, w4T_lo, nullptr, hp, NP, 128, 128);
  k_scatter_old<<<(NP+255)/256,256,0,stream>>>(oni, inv, kp0, NP, N);
  k_count<<<(E+255)/256,256,0,stream>>>(edges, deg_i, E);
  k_scan1<<<nb,256,0,stream>>>(deg_i, rowptr, bsum, N);
  k_scan2<<<1,512,0,stream>>>(bsum, nb);
  k_scan3<<<(N+255)/256,256,0,stream>>>(rowptr, bsum, cursor, N, E);
  k_fill<<<(E+255)/256,256,0,stream>>>(edges, cursor, eid, E);
  for(int base=0; base<N; base+=CH){
    int M = (N-base < CH) ? (N-base) : CH;
    k_aggcsr<<<((size_t)M*64+255)/256,256,0,stream>>>(edges, eid, rowptr, gi_t, gh_t, hidden, ahi, alo, base, M);
    k_mfma_fused<<<dim3((M+127)/128, 2),256,0,stream>>>(ahi, alo, wbig_hi, wbig_lo, rowptr, inv, hp, b_pna, out_h, base, M);
  }
  k_center<<<(N+255)/256,256,0,stream>>>(nodes, q_sub, cidx, N, Bq);
  k_cu<<<Bq,64,0,stream>>>(out_h, cidx, W_sc, cu, Bq);
  k_alpha<<<(N+3)/4,256,0,stream>>>(out_h, nodes, cu, W_sc, b_sc, kp0, out_alpha, out_keep, ca, N);
  k_cand_count<<<(N+255)/256,256,0,stream>>>(nodes, kp0, ccnt, N, Bq);
  k_cand_base<<<1,64,0,stream>>>(ccnt, cbase, ccur, Bq);
  k_cand_fill<<<(N+255)/256,256,0,stream>>>(nodes, kp0, ca, ccur, cand, N, Bq);
  k_topk3<<<Bq,256,0,stream>>>(cand, cbase, idl, nl, out_keep);
  k_keepfin<<<(N+255)/256,256,0,stream>>>(nodes, kp0, idl, nl, out_keep, N);
}